// Round 1
// baseline (4798.190 us; speedup 1.0000x reference)
//
#include <hip/hip_runtime.h>
#include <math.h>

#define SEQ 2048
#define HIDD 2048
#define NHEAD 16
#define NOPE_D 128
#define ROPE_D 64
#define VDIM_D 128
#define QRANK 1536
#define KVRANK 512
#define IHEAD 16
#define IDIM 128
#define TOPK 512
#define EPSF 1e-6f
#define SCALE_ATTN 0.07216878364870323f  /* 192^-0.5 */

// ---------------- RoPE cos/sin table (fp64 precompute) ----------------
__global__ void rope_table_kernel(float* __restrict__ cos_t, float* __restrict__ sin_t) {
    int s = blockIdx.x;
    int i = threadIdx.x;  // 0..31
    double inv = pow(10000.0, -((double)(2 * i)) / 64.0);
    double f = (double)s * inv;
    cos_t[s * 32 + i] = (float)cos(f);
    sin_t[s * 32 + i] = (float)sin(f);
}

// ---------------- generic NT GEMM: C[M,N] = alpha * A(M,K) * B(N,K)^T ----------------
__global__ __launch_bounds__(256) void gemm_nt_kernel(
    const float* __restrict__ A, const float* __restrict__ B, float* __restrict__ C,
    int M, int N, int K, int lda, int ldb, int ldc, float alpha)
{
    __shared__ float As[128][17];
    __shared__ float Bs[128][17];
    int tid = threadIdx.x;
    int tx = tid & 15, ty = tid >> 4;
    int m0 = blockIdx.x * 128, n0 = blockIdx.y * 128;
    float acc[8][8] = {};
    for (int k0 = 0; k0 < K; k0 += 16) {
        __syncthreads();
#pragma unroll
        for (int r = 0; r < 2; ++r) {
            int idx = tid + r * 256;        // 0..511
            int row = idx >> 2, c4 = idx & 3;
            int gm = m0 + row;
            float4 va = make_float4(0.f, 0.f, 0.f, 0.f);
            if (gm < M) va = *(const float4*)(A + (size_t)gm * lda + k0 + c4 * 4);
            As[row][c4 * 4 + 0] = va.x; As[row][c4 * 4 + 1] = va.y;
            As[row][c4 * 4 + 2] = va.z; As[row][c4 * 4 + 3] = va.w;
            int gn = n0 + row;
            float4 vb = make_float4(0.f, 0.f, 0.f, 0.f);
            if (gn < N) vb = *(const float4*)(B + (size_t)gn * ldb + k0 + c4 * 4);
            Bs[row][c4 * 4 + 0] = vb.x; Bs[row][c4 * 4 + 1] = vb.y;
            Bs[row][c4 * 4 + 2] = vb.z; Bs[row][c4 * 4 + 3] = vb.w;
        }
        __syncthreads();
#pragma unroll
        for (int kk = 0; kk < 16; ++kk) {
            float a[8], b[8];
#pragma unroll
            for (int i = 0; i < 8; ++i) a[i] = As[ty + 16 * i][kk];
#pragma unroll
            for (int j = 0; j < 8; ++j) b[j] = Bs[tx + 16 * j][kk];
#pragma unroll
            for (int i = 0; i < 8; ++i)
#pragma unroll
                for (int j = 0; j < 8; ++j)
                    acc[i][j] += a[i] * b[j];
        }
    }
#pragma unroll
    for (int i = 0; i < 8; ++i) {
        int gm = m0 + ty + 16 * i;
        if (gm >= M) continue;
#pragma unroll
        for (int j = 0; j < 8; ++j) {
            int gn = n0 + tx + 16 * j;
            if (gn < N) C[(size_t)gm * ldc + gn] = alpha * acc[i][j];
        }
    }
}

// ---------------- RMSNorm over a row of length n ----------------
__global__ __launch_bounds__(256) void rmsnorm_kernel(
    const float* __restrict__ in, const float* __restrict__ w, float* __restrict__ out,
    int n, int in_stride)
{
    int row = blockIdx.x, tid = threadIdx.x;
    const float* x = in + (size_t)row * in_stride;
    float4 v[2];
    int cnt = 0;
    float ss = 0.f;
    int nf4 = n >> 2;
    for (int i = tid; i < nf4; i += 256) {
        float4 t = *(const float4*)(x + i * 4);
        v[cnt++] = t;
        ss += t.x * t.x + t.y * t.y + t.z * t.z + t.w * t.w;
    }
#pragma unroll
    for (int m = 32; m; m >>= 1) ss += __shfl_xor(ss, m);
    __shared__ float red[8];
    int wid = tid >> 6;
    if ((tid & 63) == 0) red[wid] = ss;
    __syncthreads();
    if (tid == 0) {
        float s = red[0] + red[1] + red[2] + red[3];
        red[4] = rsqrtf(s / (float)n + EPSF);
    }
    __syncthreads();
    float scale = red[4];
    cnt = 0;
    for (int i = tid; i < nf4; i += 256) {
        float4 t = v[cnt++];
        float4 wv = *(const float4*)(w + i * 4);
        float4 o;
        o.x = t.x * scale * wv.x; o.y = t.y * scale * wv.y;
        o.z = t.z * scale * wv.z; o.w = t.w * scale * wv.w;
        *(float4*)(out + (size_t)row * n + i * 4) = o;
    }
}

// ---------------- LayerNorm (row length 128 fixed) ----------------
__global__ __launch_bounds__(64) void layernorm_kernel(
    const float* __restrict__ in, const float* __restrict__ w, const float* __restrict__ b,
    float* __restrict__ out)
{
    int row = blockIdx.x, tid = threadIdx.x;
    const float* x = in + (size_t)row * 128;
    float x0 = x[tid], x1 = x[tid + 64];
    float s = x0 + x1, ss = x0 * x0 + x1 * x1;
#pragma unroll
    for (int m = 32; m; m >>= 1) { s += __shfl_xor(s, m); ss += __shfl_xor(ss, m); }
    float mean = s * (1.f / 128.f);
    float var = ss * (1.f / 128.f) - mean * mean;
    float r = rsqrtf(var + EPSF);
    out[(size_t)row * 128 + tid] = (x0 - mean) * r * w[tid] + b[tid];
    out[(size_t)row * 128 + tid + 64] = (x1 - mean) * r * w[tid + 64] + b[tid + 64];
}

// ---------------- RoPE in-place: pairs (d, d+32) of a 64-dim slice ----------------
__global__ void rope_apply_kernel(
    float* __restrict__ x, const float* __restrict__ cos_t, const float* __restrict__ sin_t,
    int heads, int row_stride, int head_stride, int offset)
{
    int t = blockIdx.x * blockDim.x + threadIdx.x;
    int i = t & 31;
    int hh = (t >> 5) % heads;
    int r = t / (32 * heads);
    if (r >= SEQ) return;
    float* p = x + (size_t)r * row_stride + hh * head_stride + offset;
    float c = cos_t[r * 32 + i], s = sin_t[r * 32 + i];
    float x1 = p[i], x2 = p[i + 32];
    p[i] = x1 * c - x2 * s;
    p[i + 32] = x2 * c + x1 * s;
}

// ---------------- indexer scores: score[q,k] = sum_h iw[q,h]*relu(iq[q,h,:].ik[k,:]) ----------------
__global__ __launch_bounds__(256) void idx_scores_kernel(
    const float* __restrict__ iq,   // (S,16,128)
    const float* __restrict__ ik,   // (S,128)
    const float* __restrict__ iw,   // (S,16)
    float* __restrict__ scores)     // (S,S)
{
    int q0 = blockIdx.x * 64, k0 = blockIdx.y * 64;
    int tid = threadIdx.x;
    int tx = tid & 15, ty = tid >> 4;
    if (k0 > q0 + 63) {  // whole tile above diagonal
        for (int t = tid; t < 64 * 64; t += 256) {
            int r = t >> 6, c = t & 63;
            scores[(size_t)(q0 + r) * SEQ + k0 + c] = -INFINITY;
        }
        return;
    }
    __shared__ float iks[64][132];
    __shared__ float iqs[64][132];
    __shared__ float iws[64][16];
    for (int t = tid; t < 64 * 32; t += 256) {
        int r = t >> 5, c4 = t & 31;
        *(float4*)&iks[r][c4 * 4] = *(const float4*)(ik + (size_t)(k0 + r) * 128 + c4 * 4);
    }
    for (int t = tid; t < 64 * 16; t += 256) {
        int r = t >> 4, c = t & 15;
        iws[r][c] = iw[(size_t)(q0 + r) * 16 + c];
    }
    float acc[4][4] = {};
    for (int h = 0; h < 16; ++h) {
        __syncthreads();
        for (int t = tid; t < 64 * 32; t += 256) {
            int r = t >> 5, c4 = t & 31;
            *(float4*)&iqs[r][c4 * 4] = *(const float4*)(iq + ((size_t)(q0 + r) * 16 + h) * 128 + c4 * 4);
        }
        __syncthreads();
        float dot[4][4] = {};
        for (int d = 0; d < 128; ++d) {
            float a[4], b[4];
#pragma unroll
            for (int i = 0; i < 4; ++i) a[i] = iqs[ty + 16 * i][d];
#pragma unroll
            for (int j = 0; j < 4; ++j) b[j] = iks[tx + 16 * j][d];
#pragma unroll
            for (int i = 0; i < 4; ++i)
#pragma unroll
                for (int j = 0; j < 4; ++j)
                    dot[i][j] += a[i] * b[j];
        }
#pragma unroll
        for (int i = 0; i < 4; ++i)
#pragma unroll
            for (int j = 0; j < 4; ++j)
                acc[i][j] += iws[ty + 16 * i][h] * fmaxf(dot[i][j], 0.f);
    }
#pragma unroll
    for (int i = 0; i < 4; ++i) {
        int q = q0 + ty + 16 * i;
#pragma unroll
        for (int j = 0; j < 4; ++j) {
            int k = k0 + tx + 16 * j;
            scores[(size_t)q * SEQ + k] = (k <= q) ? acc[i][j] : -INFINITY;
        }
    }
}

// ---------------- top-512 per row via bitonic sort (stable jax tie semantics) ----------------
__global__ __launch_bounds__(1024) void topk_kernel(
    const float* __restrict__ scores, int* __restrict__ sel)
{
    int qi = blockIdx.x, tid = threadIdx.x;
    __shared__ unsigned long long keys[2048];
    const float* srow = scores + (size_t)qi * SEQ;
#pragma unroll
    for (int r = 0; r < 2; ++r) {
        int k = tid + r * 1024;
        unsigned u = __float_as_uint(srow[k]);
        unsigned mv = (u & 0x80000000u) ? ~u : (u | 0x80000000u);
        keys[k] = ((unsigned long long)mv << 32) | (unsigned)(2047 - k);
    }
    for (int ksz = 2; ksz <= 2048; ksz <<= 1) {
        for (int j = ksz >> 1; j > 0; j >>= 1) {
            __syncthreads();
#pragma unroll 1
            for (int r = 0; r < 2; ++r) {
                int i = tid + r * 1024;
                int ixj = i ^ j;
                if (ixj > i) {
                    unsigned long long a = keys[i], b = keys[ixj];
                    bool dir = ((i & ksz) == 0);
                    if ((a < b) == dir) { keys[i] = b; keys[ixj] = a; }  // descending
                }
            }
        }
    }
    __syncthreads();
    if (tid < TOPK) {
        int k = 2047 - (int)(keys[tid] & 0xFFFFFFFFu);
        sel[(size_t)qi * TOPK + tid] = (tid <= qi) ? k : -1;
    }
}

// ---------------- sparse attention over selected keys ----------------
__global__ __launch_bounds__(256) void attn_kernel(
    const float* __restrict__ q,    // (S,16,192) roped
    const float* __restrict__ kv,   // (S,16,256): [0:128]=k_nope, [128:256]=v
    const float* __restrict__ ckv,  // (S,576): [512:576]=roped k_pe
    const int* __restrict__ sel,    // (S,512)
    float* __restrict__ out)        // (S,16,128)
{
    int qi = blockIdx.x, tid = threadIdx.x;
    int h = tid >> 4, g = tid & 15;
    __shared__ float qs[16 * 192];
    const float4* qrow = (const float4*)(q + (size_t)qi * 3072);
    for (int t = tid; t < 768; t += 256) ((float4*)qs)[t] = qrow[t];
    __syncthreads();
    const float* qh = qs + h * 192;
    float m = -1e30f, l = 0.f;
    float acc[8] = {};
    int nv = min(TOPK, qi + 1);
    for (int j = 0; j < nv; ++j) {
        int k = sel[(size_t)qi * TOPK + j];
        const float* kvrow = kv + ((size_t)k * 16 + h) * 256;
        const float* kperow = ckv + (size_t)k * 576 + 512;
        float4 a0 = ((const float4*)qh)[g];
        float4 b0 = ((const float4*)kvrow)[g];
        float part = a0.x * b0.x + a0.y * b0.y + a0.z * b0.z + a0.w * b0.w;
        float4 a1 = ((const float4*)qh)[g + 16];
        float4 b1 = ((const float4*)kvrow)[g + 16];
        part += a1.x * b1.x + a1.y * b1.y + a1.z * b1.z + a1.w * b1.w;
        float4 a2 = ((const float4*)qh)[g + 32];
        float4 b2 = ((const float4*)kperow)[g];
        part += a2.x * b2.x + a2.y * b2.y + a2.z * b2.z + a2.w * b2.w;
        part += __shfl_xor(part, 1);
        part += __shfl_xor(part, 2);
        part += __shfl_xor(part, 4);
        part += __shfl_xor(part, 8);
        float sc = part * SCALE_ATTN;
        float mn = fmaxf(m, sc);
        float so = __expf(m - mn);
        float p = __expf(sc - mn);
        l = l * so + p;
        const float4* vrow = (const float4*)(kvrow + 128);
        float4 v0 = vrow[g * 2], v1 = vrow[g * 2 + 1];
        acc[0] = acc[0] * so + p * v0.x; acc[1] = acc[1] * so + p * v0.y;
        acc[2] = acc[2] * so + p * v0.z; acc[3] = acc[3] * so + p * v0.w;
        acc[4] = acc[4] * so + p * v1.x; acc[5] = acc[5] * so + p * v1.y;
        acc[6] = acc[6] * so + p * v1.z; acc[7] = acc[7] * so + p * v1.w;
        m = mn;
    }
    float invl = 1.f / l;
    float* orow = out + ((size_t)qi * 16 + h) * 128 + g * 8;
    float4 o0 = { acc[0] * invl, acc[1] * invl, acc[2] * invl, acc[3] * invl };
    float4 o1 = { acc[4] * invl, acc[5] * invl, acc[6] * invl, acc[7] * invl };
    ((float4*)orow)[0] = o0;
    ((float4*)orow)[1] = o1;
}

// ---------------- launcher ----------------
extern "C" void kernel_launch(void* const* d_in, const int* in_sizes, int n_in,
                              void* d_out, int out_size, void* d_ws, size_t ws_size,
                              hipStream_t stream) {
    (void)in_sizes; (void)n_in; (void)out_size; (void)ws_size;
    const float* hidden      = (const float*)d_in[0];
    const float* q_a_w       = (const float*)d_in[1];
    const float* q_a_ln_w    = (const float*)d_in[2];
    const float* q_b_w       = (const float*)d_in[3];
    const float* kv_a_w      = (const float*)d_in[4];
    const float* kv_a_ln_w   = (const float*)d_in[5];
    const float* kv_b_w      = (const float*)d_in[6];
    const float* o_w         = (const float*)d_in[7];
    const float* idx_wq_b_w  = (const float*)d_in[8];
    const float* idx_wk_w    = (const float*)d_in[9];
    const float* idx_kn_w    = (const float*)d_in[10];
    const float* idx_kn_b    = (const float*)d_in[11];
    const float* idx_wproj_w = (const float*)d_in[12];
    float* out = (float*)d_out;

    char* ws = (char*)d_ws;
    size_t off = 0;
    auto alloc = [&](size_t nbytes) -> void* {
        void* p = ws + off;
        off = (off + nbytes + 255) & ~(size_t)255;
        return p;
    };
    float* cos_t = (float*)alloc((size_t)SEQ * 32 * 4);
    float* sin_t = (float*)alloc((size_t)SEQ * 32 * 4);
    float* qr    = (float*)alloc((size_t)SEQ * QRANK * 4);
    float* qbuf  = (float*)alloc((size_t)SEQ * 3072 * 4);
    float* ckv   = (float*)alloc((size_t)SEQ * 576 * 4);
    float* ckvn  = (float*)alloc((size_t)SEQ * KVRANK * 4);
    float* kvbuf = (float*)alloc((size_t)SEQ * 4096 * 4);
    float* iqb   = (float*)alloc((size_t)SEQ * 2048 * 4);
    float* ikb   = (float*)alloc((size_t)SEQ * 128 * 4);
    float* iwb   = (float*)alloc((size_t)SEQ * 16 * 4);
    float* scores = (float*)alloc((size_t)SEQ * SEQ * 4);
    float* attno  = (float*)alloc((size_t)SEQ * 2048 * 4);
    int*   sel    = (int*)alloc((size_t)SEQ * TOPK * 4);

    rope_table_kernel<<<dim3(SEQ), dim3(32), 0, stream>>>(cos_t, sin_t);

    // qr = rmsnorm(hidden @ q_a_w^T) * ln_w
    gemm_nt_kernel<<<dim3(16, 12), 256, 0, stream>>>(hidden, q_a_w, qr, SEQ, QRANK, HIDD, HIDD, HIDD, QRANK, 1.f);
    rmsnorm_kernel<<<SEQ, 256, 0, stream>>>(qr, q_a_ln_w, qr, QRANK, QRANK);

    // q = qr @ q_b_w^T ; rope on [128:192] per head
    gemm_nt_kernel<<<dim3(16, 24), 256, 0, stream>>>(qr, q_b_w, qbuf, SEQ, 3072, QRANK, QRANK, QRANK, 3072, 1.f);
    rope_apply_kernel<<<(SEQ * 16 * 32) / 256, 256, 0, stream>>>(qbuf, cos_t, sin_t, 16, 3072, 192, 128);

    // ckv = hidden @ kv_a_w^T ; rope k_pe in place; rmsnorm c_kv -> ckvn
    gemm_nt_kernel<<<dim3(16, 5), 256, 0, stream>>>(hidden, kv_a_w, ckv, SEQ, 576, HIDD, HIDD, HIDD, 576, 1.f);
    rope_apply_kernel<<<(SEQ * 32) / 256, 256, 0, stream>>>(ckv, cos_t, sin_t, 1, 576, 0, 512);
    rmsnorm_kernel<<<SEQ, 256, 0, stream>>>(ckv, kv_a_ln_w, ckvn, KVRANK, 576);

    // kv = ckvn @ kv_b_w^T
    gemm_nt_kernel<<<dim3(16, 32), 256, 0, stream>>>(ckvn, kv_b_w, kvbuf, SEQ, 4096, KVRANK, KVRANK, KVRANK, 4096, 1.f);

    // indexer q: iq = qr @ idx_wq_b_w^T ; rope [0:64] per head
    gemm_nt_kernel<<<dim3(16, 16), 256, 0, stream>>>(qr, idx_wq_b_w, iqb, SEQ, 2048, QRANK, QRANK, QRANK, 2048, 1.f);
    rope_apply_kernel<<<(SEQ * 16 * 32) / 256, 256, 0, stream>>>(iqb, cos_t, sin_t, 16, 2048, 128, 0);

    // indexer k: ik = rope(layernorm(hidden @ idx_wk_w^T))
    gemm_nt_kernel<<<dim3(16, 1), 256, 0, stream>>>(hidden, idx_wk_w, ikb, SEQ, IDIM, HIDD, HIDD, HIDD, IDIM, 1.f);
    layernorm_kernel<<<SEQ, 64, 0, stream>>>(ikb, idx_kn_w, idx_kn_b, ikb);
    rope_apply_kernel<<<(SEQ * 32) / 256, 256, 0, stream>>>(ikb, cos_t, sin_t, 1, 128, 0, 0);

    // iw = hidden @ idx_wproj_w^T * 0.25
    gemm_nt_kernel<<<dim3(16, 1), 256, 0, stream>>>(hidden, idx_wproj_w, iwb, SEQ, IHEAD, HIDD, HIDD, HIDD, IHEAD, 0.25f);

    // indexer scores + causal mask
    idx_scores_kernel<<<dim3(32, 32), 256, 0, stream>>>(iqb, ikb, iwb, scores);

    // exact top-512 per row
    topk_kernel<<<SEQ, 1024, 0, stream>>>(scores, sel);

    // sparse attention
    attn_kernel<<<SEQ, 256, 0, stream>>>(qbuf, kvbuf, ckv, sel, attno);

    // output = attno @ o_w^T
    gemm_nt_kernel<<<dim3(16, 16), 256, 0, stream>>>(attno, o_w, out, SEQ, HIDD, 2048, 2048, 2048, HIDD, 1.f);
}

// Round 2
// 4129.365 us; speedup vs baseline: 1.1620x; 1.1620x over previous
//
#include <hip/hip_runtime.h>
#include <hip/hip_bf16.h>
#include <math.h>

#define SEQ 2048
#define HIDD 2048
#define NHEAD 16
#define NOPE_D 128
#define ROPE_D 64
#define VDIM_D 128
#define QRANK 1536
#define KVRANK 512
#define IHEAD 16
#define IDIM 128
#define TOPK 512
#define EPSF 1e-6f
#define SCALE_ATTN 0.07216878364870323f  /* 192^-0.5 */
#define KB 16

__device__ inline unsigned short f2bf(float f) {
    unsigned u = __float_as_uint(f);
    unsigned r = (u + 0x7FFFu + ((u >> 16) & 1u)) >> 16;
    return (unsigned short)r;
}
__device__ inline float bf2f(unsigned short b) {
    return __uint_as_float(((unsigned)b) << 16);
}

// ---------------- RoPE cos/sin table (fp64 precompute) ----------------
__global__ void rope_table_kernel(float* __restrict__ cos_t, float* __restrict__ sin_t) {
    int s = blockIdx.x;
    int i = threadIdx.x;  // 0..31
    double inv = pow(10000.0, -((double)(2 * i)) / 64.0);
    double f = (double)s * inv;
    cos_t[s * 32 + i] = (float)cos(f);
    sin_t[s * 32 + i] = (float)sin(f);
}

// ---------------- generic NT GEMM: C[M,N] = alpha * A(M,K) * B(N,K)^T ----------------
__global__ __launch_bounds__(256) void gemm_nt_kernel(
    const float* __restrict__ A, const float* __restrict__ B, float* __restrict__ C,
    int M, int N, int K, int lda, int ldb, int ldc, float alpha)
{
    __shared__ float As[128][17];
    __shared__ float Bs[128][17];
    int tid = threadIdx.x;
    int tx = tid & 15, ty = tid >> 4;
    int m0 = blockIdx.x * 128, n0 = blockIdx.y * 128;
    float acc[8][8] = {};
    for (int k0 = 0; k0 < K; k0 += 16) {
        __syncthreads();
#pragma unroll
        for (int r = 0; r < 2; ++r) {
            int idx = tid + r * 256;        // 0..511
            int row = idx >> 2, c4 = idx & 3;
            int gm = m0 + row;
            float4 va = make_float4(0.f, 0.f, 0.f, 0.f);
            if (gm < M) va = *(const float4*)(A + (size_t)gm * lda + k0 + c4 * 4);
            As[row][c4 * 4 + 0] = va.x; As[row][c4 * 4 + 1] = va.y;
            As[row][c4 * 4 + 2] = va.z; As[row][c4 * 4 + 3] = va.w;
            int gn = n0 + row;
            float4 vb = make_float4(0.f, 0.f, 0.f, 0.f);
            if (gn < N) vb = *(const float4*)(B + (size_t)gn * ldb + k0 + c4 * 4);
            Bs[row][c4 * 4 + 0] = vb.x; Bs[row][c4 * 4 + 1] = vb.y;
            Bs[row][c4 * 4 + 2] = vb.z; Bs[row][c4 * 4 + 3] = vb.w;
        }
        __syncthreads();
#pragma unroll
        for (int kk = 0; kk < 16; ++kk) {
            float a[8], b[8];
#pragma unroll
            for (int i = 0; i < 8; ++i) a[i] = As[ty + 16 * i][kk];
#pragma unroll
            for (int j = 0; j < 8; ++j) b[j] = Bs[tx + 16 * j][kk];
#pragma unroll
            for (int i = 0; i < 8; ++i)
#pragma unroll
                for (int j = 0; j < 8; ++j)
                    acc[i][j] += a[i] * b[j];
        }
    }
#pragma unroll
    for (int i = 0; i < 8; ++i) {
        int gm = m0 + ty + 16 * i;
        if (gm >= M) continue;
#pragma unroll
        for (int j = 0; j < 8; ++j) {
            int gn = n0 + tx + 16 * j;
            if (gn < N) C[(size_t)gm * ldc + gn] = alpha * acc[i][j];
        }
    }
}

// ---------------- batched GEMM (per-head): NT or NN, mixed f32/bf16 A/C ----------------
// NT: C[m,n] = sum_k A[m,k] * B[n,k]   (B row-major N x K)
// NN: C[m,n] = sum_k A[m,k] * B[k,n]   (B row-major K x N)
template <typename TA, typename TC, bool NT>
__global__ __launch_bounds__(256) void gemm_batched_kernel(
    const TA* __restrict__ A, const float* __restrict__ B, TC* __restrict__ C,
    int M, int N, int K, int lda, int ldb, int ldc,
    long aBatch, long bBatch, long cBatch, float alpha)
{
    __shared__ float Ash[128 * 17];
    __shared__ float Bsh[128 * 17];
    int z = blockIdx.z;
    const TA* Az = A + (size_t)z * aBatch;
    const float* Bz = B + (size_t)z * bBatch;
    TC* Cz = C + (size_t)z * cBatch;
    int tid = threadIdx.x;
    int tx = tid & 15, ty = tid >> 4;
    int m0 = blockIdx.x * 128, n0 = blockIdx.y * 128;
    float acc[8][8] = {};
    for (int k0 = 0; k0 < K; k0 += 16) {
        __syncthreads();
        // stage A tile (128 rows x 16 k)
#pragma unroll
        for (int r = 0; r < 2; ++r) {
            int idx = tid + r * 256;
            int row = idx >> 2, c4 = idx & 3;
            int gm = m0 + row;
            float d[4] = {0.f, 0.f, 0.f, 0.f};
            if (gm < M) {
                const TA* src = Az + (size_t)gm * lda + k0 + c4 * 4;
                if constexpr (sizeof(TA) == 4) {
                    float4 v = *(const float4*)src;
                    d[0] = v.x; d[1] = v.y; d[2] = v.z; d[3] = v.w;
                } else {
                    ushort4 v = *(const ushort4*)src;
                    d[0] = bf2f(v.x); d[1] = bf2f(v.y); d[2] = bf2f(v.z); d[3] = bf2f(v.w);
                }
            }
#pragma unroll
            for (int e = 0; e < 4; ++e) Ash[row * 17 + c4 * 4 + e] = d[e];
        }
        // stage B tile
        if constexpr (NT) {
#pragma unroll
            for (int r = 0; r < 2; ++r) {
                int idx = tid + r * 256;
                int row = idx >> 2, c4 = idx & 3;
                int gn = n0 + row;
                float4 v = make_float4(0.f, 0.f, 0.f, 0.f);
                if (gn < N) v = *(const float4*)(Bz + (size_t)gn * ldb + k0 + c4 * 4);
                Bsh[row * 17 + c4 * 4 + 0] = v.x; Bsh[row * 17 + c4 * 4 + 1] = v.y;
                Bsh[row * 17 + c4 * 4 + 2] = v.z; Bsh[row * 17 + c4 * 4 + 3] = v.w;
            }
        } else {
            // B tile: 16 k-rows x 128 n-cols, stride 136 (16B aligned, conflict-free reads)
            for (int t = tid; t < 16 * 32; t += 256) {
                int row = t >> 5, c4 = t & 31;
                float4 v = *(const float4*)(Bz + (size_t)(k0 + row) * ldb + n0 + c4 * 4);
                Bsh[row * 136 + c4 * 4 + 0] = v.x; Bsh[row * 136 + c4 * 4 + 1] = v.y;
                Bsh[row * 136 + c4 * 4 + 2] = v.z; Bsh[row * 136 + c4 * 4 + 3] = v.w;
            }
        }
        __syncthreads();
#pragma unroll
        for (int kk = 0; kk < 16; ++kk) {
            float a[8], b[8];
#pragma unroll
            for (int i = 0; i < 8; ++i) a[i] = Ash[(ty + 16 * i) * 17 + kk];
#pragma unroll
            for (int j = 0; j < 8; ++j) {
                if constexpr (NT) b[j] = Bsh[(tx + 16 * j) * 17 + kk];
                else              b[j] = Bsh[kk * 136 + tx + 16 * j];
            }
#pragma unroll
            for (int i = 0; i < 8; ++i)
#pragma unroll
                for (int j = 0; j < 8; ++j)
                    acc[i][j] += a[i] * b[j];
        }
    }
#pragma unroll
    for (int i = 0; i < 8; ++i) {
        int gm = m0 + ty + 16 * i;
        if (gm >= M) continue;
#pragma unroll
        for (int j = 0; j < 8; ++j) {
            int gn = n0 + tx + 16 * j;
            if (gn < N) {
                float v = alpha * acc[i][j];
                if constexpr (sizeof(TC) == 4) Cz[(size_t)gm * ldc + gn] = v;
                else {
                    __hip_bfloat16_raw rw; rw.x = f2bf(v);
                    Cz[(size_t)gm * ldc + gn] = __hip_bfloat16(rw);
                }
            }
        }
    }
}

// ---------------- RMSNorm over a row of length n ----------------
__global__ __launch_bounds__(256) void rmsnorm_kernel(
    const float* __restrict__ in, const float* __restrict__ w, float* __restrict__ out,
    int n, int in_stride)
{
    int row = blockIdx.x, tid = threadIdx.x;
    const float* x = in + (size_t)row * in_stride;
    float4 v[2];
    int cnt = 0;
    float ss = 0.f;
    int nf4 = n >> 2;
    for (int i = tid; i < nf4; i += 256) {
        float4 t = *(const float4*)(x + i * 4);
        v[cnt++] = t;
        ss += t.x * t.x + t.y * t.y + t.z * t.z + t.w * t.w;
    }
#pragma unroll
    for (int m = 32; m; m >>= 1) ss += __shfl_xor(ss, m);
    __shared__ float red[8];
    int wid = tid >> 6;
    if ((tid & 63) == 0) red[wid] = ss;
    __syncthreads();
    if (tid == 0) {
        float s = red[0] + red[1] + red[2] + red[3];
        red[4] = rsqrtf(s / (float)n + EPSF);
    }
    __syncthreads();
    float scale = red[4];
    cnt = 0;
    for (int i = tid; i < nf4; i += 256) {
        float4 t = v[cnt++];
        float4 wv = *(const float4*)(w + i * 4);
        float4 o;
        o.x = t.x * scale * wv.x; o.y = t.y * scale * wv.y;
        o.z = t.z * scale * wv.z; o.w = t.w * scale * wv.w;
        *(float4*)(out + (size_t)row * n + i * 4) = o;
    }
}

// ---------------- LayerNorm (row length 128 fixed) ----------------
__global__ __launch_bounds__(64) void layernorm_kernel(
    const float* __restrict__ in, const float* __restrict__ w, const float* __restrict__ b,
    float* __restrict__ out)
{
    int row = blockIdx.x, tid = threadIdx.x;
    const float* x = in + (size_t)row * 128;
    float x0 = x[tid], x1 = x[tid + 64];
    float s = x0 + x1, ss = x0 * x0 + x1 * x1;
#pragma unroll
    for (int m = 32; m; m >>= 1) { s += __shfl_xor(s, m); ss += __shfl_xor(ss, m); }
    float mean = s * (1.f / 128.f);
    float var = ss * (1.f / 128.f) - mean * mean;
    float r = rsqrtf(var + EPSF);
    out[(size_t)row * 128 + tid] = (x0 - mean) * r * w[tid] + b[tid];
    out[(size_t)row * 128 + tid + 64] = (x1 - mean) * r * w[tid + 64] + b[tid + 64];
}

// ---------------- RoPE in-place: pairs (d, d+32) of a 64-dim slice ----------------
__global__ void rope_apply_kernel(
    float* __restrict__ x, const float* __restrict__ cos_t, const float* __restrict__ sin_t,
    int heads, int row_stride, int head_stride, int offset)
{
    int t = blockIdx.x * blockDim.x + threadIdx.x;
    int i = t & 31;
    int hh = (t >> 5) % heads;
    int r = t / (32 * heads);
    if (r >= SEQ) return;
    float* p = x + (size_t)r * row_stride + hh * head_stride + offset;
    float c = cos_t[r * 32 + i], s = sin_t[r * 32 + i];
    float x1 = p[i], x2 = p[i + 32];
    p[i] = x1 * c - x2 * s;
    p[i + 32] = x2 * c + x1 * s;
}

// ---------------- indexer scores ----------------
__global__ __launch_bounds__(256) void idx_scores_kernel(
    const float* __restrict__ iq,   // (S,16,128)
    const float* __restrict__ ik,   // (S,128)
    const float* __restrict__ iw,   // (S,16)
    float* __restrict__ scores)     // (S,S)
{
    int q0 = blockIdx.x * 64, k0 = blockIdx.y * 64;
    int tid = threadIdx.x;
    int tx = tid & 15, ty = tid >> 4;
    if (k0 > q0 + 63) {
        for (int t = tid; t < 64 * 64; t += 256) {
            int r = t >> 6, c = t & 63;
            scores[(size_t)(q0 + r) * SEQ + k0 + c] = -INFINITY;
        }
        return;
    }
    __shared__ float iks[64][132];
    __shared__ float iqs[64][132];
    __shared__ float iws[64][16];
    for (int t = tid; t < 64 * 32; t += 256) {
        int r = t >> 5, c4 = t & 31;
        *(float4*)&iks[r][c4 * 4] = *(const float4*)(ik + (size_t)(k0 + r) * 128 + c4 * 4);
    }
    for (int t = tid; t < 64 * 16; t += 256) {
        int r = t >> 4, c = t & 15;
        iws[r][c] = iw[(size_t)(q0 + r) * 16 + c];
    }
    float acc[4][4] = {};
    for (int h = 0; h < 16; ++h) {
        __syncthreads();
        for (int t = tid; t < 64 * 32; t += 256) {
            int r = t >> 5, c4 = t & 31;
            *(float4*)&iqs[r][c4 * 4] = *(const float4*)(iq + ((size_t)(q0 + r) * 16 + h) * 128 + c4 * 4);
        }
        __syncthreads();
        float dot[4][4] = {};
        for (int d = 0; d < 128; ++d) {
            float a[4], b[4];
#pragma unroll
            for (int i = 0; i < 4; ++i) a[i] = iqs[ty + 16 * i][d];
#pragma unroll
            for (int j = 0; j < 4; ++j) b[j] = iks[tx + 16 * j][d];
#pragma unroll
            for (int i = 0; i < 4; ++i)
#pragma unroll
                for (int j = 0; j < 4; ++j)
                    dot[i][j] += a[i] * b[j];
        }
#pragma unroll
        for (int i = 0; i < 4; ++i)
#pragma unroll
            for (int j = 0; j < 4; ++j)
                acc[i][j] += iws[ty + 16 * i][h] * fmaxf(dot[i][j], 0.f);
    }
#pragma unroll
    for (int i = 0; i < 4; ++i) {
        int q = q0 + ty + 16 * i;
#pragma unroll
        for (int j = 0; j < 4; ++j) {
            int k = k0 + tx + 16 * j;
            scores[(size_t)q * SEQ + k] = (k <= q) ? acc[i][j] : -INFINITY;
        }
    }
}

// ---------------- top-512 per row via bitonic sort ----------------
__global__ __launch_bounds__(1024) void topk_kernel(
    const float* __restrict__ scores, int* __restrict__ sel)
{
    int qi = blockIdx.x, tid = threadIdx.x;
    __shared__ unsigned long long keys[2048];
    const float* srow = scores + (size_t)qi * SEQ;
#pragma unroll
    for (int r = 0; r < 2; ++r) {
        int k = tid + r * 1024;
        unsigned u = __float_as_uint(srow[k]);
        unsigned mv = (u & 0x80000000u) ? ~u : (u | 0x80000000u);
        keys[k] = ((unsigned long long)mv << 32) | (unsigned)(2047 - k);
    }
    for (int ksz = 2; ksz <= 2048; ksz <<= 1) {
        for (int j = ksz >> 1; j > 0; j >>= 1) {
            __syncthreads();
#pragma unroll 1
            for (int r = 0; r < 2; ++r) {
                int i = tid + r * 1024;
                int ixj = i ^ j;
                if (ixj > i) {
                    unsigned long long a = keys[i], b = keys[ixj];
                    bool dir = ((i & ksz) == 0);
                    if ((a < b) == dir) { keys[i] = b; keys[ixj] = a; }
                }
            }
        }
    }
    __syncthreads();
    if (tid < TOPK) {
        int k = 2047 - (int)(keys[tid] & 0xFFFFFFFFu);
        sel[(size_t)qi * TOPK + tid] = (tid <= qi) ? k : -1;
    }
}

// ---------------- absorbed sparse attention ----------------
// score[h,k] = qabs[h,:]·ckvn[k,:] + qpe[h,:]·kpe[k,:];  ocomp[h,:] = softmax·ckvn
__global__ __launch_bounds__(256) void attn_abs_kernel(
    const __hip_bfloat16* __restrict__ qabs,  // (S,16,512) bf16
    const float* __restrict__ qsrc,           // qbuf (S,16,192), qpe at +128
    const float* __restrict__ ckvn,           // (S,512)
    const float* __restrict__ ckv,            // (S,576), kpe at +512
    const int* __restrict__ sel,              // (S,512)
    __hip_bfloat16* __restrict__ ocomp)       // (S,16,512) bf16, normalized
{
    int qi = blockIdx.x;
    int tid = threadIdx.x;
    int h = tid >> 4, g = tid & 15;
    __shared__ float cs[KB][512];
    __shared__ float ps[KB][64];
    __shared__ int selb[KB];

    // q fragments (rotated slice layout: lane g holds r = g*32 + ((j+g)&7)*4 ..+3)
    float4 qa[8];
    const unsigned short* qrow = (const unsigned short*)(qabs + ((size_t)qi * 16 + h) * 512);
#pragma unroll
    for (int j = 0; j < 8; ++j) {
        int r = g * 32 + ((j + g) & 7) * 4;
        ushort4 u = *(const ushort4*)(qrow + r);
        qa[j].x = bf2f(u.x); qa[j].y = bf2f(u.y); qa[j].z = bf2f(u.z); qa[j].w = bf2f(u.w);
    }
    float4 qp = *(const float4*)(qsrc + (size_t)qi * 3072 + h * 192 + 128 + g * 4);

    float m = -1e30f, l = 0.f;
    float4 oc[8] = {};
    int nv = min(TOPK, qi + 1);

    for (int j0 = 0; j0 < nv; j0 += KB) {
        int nb = min(KB, nv - j0);
        __syncthreads();
        if (tid < nb) selb[tid] = sel[(size_t)qi * TOPK + j0 + tid];
        __syncthreads();
        for (int t = tid; t < nb * 128; t += 256) {
            int key = t >> 7, f4 = t & 127;
            ((float4*)cs[key])[f4] = ((const float4*)(ckvn + (size_t)selb[key] * 512))[f4];
        }
        for (int t = tid; t < nb * 16; t += 256) {
            int key = t >> 4, f4 = t & 15;
            ((float4*)ps[key])[f4] = ((const float4*)(ckv + (size_t)selb[key] * 576 + 512))[f4];
        }
        __syncthreads();
        for (int kk = 0; kk < nb; ++kk) {
            float4 ck[8];
            const float* crow = cs[kk];
#pragma unroll
            for (int j = 0; j < 8; ++j) {
                int r = g * 32 + ((j + g) & 7) * 4;
                ck[j] = *(const float4*)(crow + r);
            }
            float4 pe = *(const float4*)(ps[kk] + g * 4);
            float part = qp.x * pe.x + qp.y * pe.y + qp.z * pe.z + qp.w * pe.w;
#pragma unroll
            for (int j = 0; j < 8; ++j)
                part += qa[j].x * ck[j].x + qa[j].y * ck[j].y + qa[j].z * ck[j].z + qa[j].w * ck[j].w;
            part += __shfl_xor(part, 1);
            part += __shfl_xor(part, 2);
            part += __shfl_xor(part, 4);
            part += __shfl_xor(part, 8);
            float sc = part * SCALE_ATTN;
            if (sc - m > 8.f) {  // deferred-max rescale (T13)
                float so = __expf(m - sc);
                l *= so;
#pragma unroll
                for (int j = 0; j < 8; ++j) {
                    oc[j].x *= so; oc[j].y *= so; oc[j].z *= so; oc[j].w *= so;
                }
                m = sc;
            }
            float p = __expf(sc - m);
            l += p;
#pragma unroll
            for (int j = 0; j < 8; ++j) {
                oc[j].x += p * ck[j].x; oc[j].y += p * ck[j].y;
                oc[j].z += p * ck[j].z; oc[j].w += p * ck[j].w;
            }
        }
    }
    float invl = 1.f / l;
    unsigned short* orow = (unsigned short*)(ocomp + ((size_t)qi * 16 + h) * 512);
#pragma unroll
    for (int j = 0; j < 8; ++j) {
        int r = g * 32 + ((j + g) & 7) * 4;
        ushort4 o;
        o.x = f2bf(oc[j].x * invl); o.y = f2bf(oc[j].y * invl);
        o.z = f2bf(oc[j].z * invl); o.w = f2bf(oc[j].w * invl);
        *(ushort4*)(orow + r) = o;
    }
}

// ---------------- launcher ----------------
extern "C" void kernel_launch(void* const* d_in, const int* in_sizes, int n_in,
                              void* d_out, int out_size, void* d_ws, size_t ws_size,
                              hipStream_t stream) {
    (void)in_sizes; (void)n_in; (void)out_size; (void)ws_size;
    const float* hidden      = (const float*)d_in[0];
    const float* q_a_w       = (const float*)d_in[1];
    const float* q_a_ln_w    = (const float*)d_in[2];
    const float* q_b_w       = (const float*)d_in[3];
    const float* kv_a_w      = (const float*)d_in[4];
    const float* kv_a_ln_w   = (const float*)d_in[5];
    const float* kv_b_w      = (const float*)d_in[6];
    const float* o_w         = (const float*)d_in[7];
    const float* idx_wq_b_w  = (const float*)d_in[8];
    const float* idx_wk_w    = (const float*)d_in[9];
    const float* idx_kn_w    = (const float*)d_in[10];
    const float* idx_kn_b    = (const float*)d_in[11];
    const float* idx_wproj_w = (const float*)d_in[12];
    float* out = (float*)d_out;

    char* ws = (char*)d_ws;
    size_t off = 0;
    auto alloc = [&](size_t nbytes) -> void* {
        void* p = ws + off;
        off = (off + nbytes + 255) & ~(size_t)255;
        return p;
    };
    // persistent
    float* cos_t = (float*)alloc((size_t)SEQ * 32 * 4);
    float* sin_t = (float*)alloc((size_t)SEQ * 32 * 4);
    float* qbuf  = (float*)alloc((size_t)SEQ * 3072 * 4);
    float* ckv   = (float*)alloc((size_t)SEQ * 576 * 4);
    float* ckvn  = (float*)alloc((size_t)SEQ * KVRANK * 4);
    int*   sel   = (int*)alloc((size_t)SEQ * TOPK * 4);
    float* attno = (float*)alloc((size_t)SEQ * 2048 * 4);
    size_t mark = off;
    // transients (dead after topk)
    float* qr    = (float*)alloc((size_t)SEQ * QRANK * 4);
    float* iqb   = (float*)alloc((size_t)SEQ * 2048 * 4);
    float* ikb   = (float*)alloc((size_t)SEQ * 128 * 4);
    float* iwb   = (float*)alloc((size_t)SEQ * 16 * 4);
    float* scores = (float*)alloc((size_t)SEQ * SEQ * 4);
    // overlay region (alive after topk)
    off = mark;
    __hip_bfloat16* qabsb = (__hip_bfloat16*)alloc((size_t)SEQ * 16 * 512 * 2);
    __hip_bfloat16* ocomp = (__hip_bfloat16*)alloc((size_t)SEQ * 16 * 512 * 2);

    rope_table_kernel<<<dim3(SEQ), dim3(32), 0, stream>>>(cos_t, sin_t);

    // qr = rmsnorm(hidden @ q_a_w^T) * ln_w
    gemm_nt_kernel<<<dim3(16, 12), 256, 0, stream>>>(hidden, q_a_w, qr, SEQ, QRANK, HIDD, HIDD, HIDD, QRANK, 1.f);
    rmsnorm_kernel<<<SEQ, 256, 0, stream>>>(qr, q_a_ln_w, qr, QRANK, QRANK);

    // q = qr @ q_b_w^T ; rope on [128:192] per head
    gemm_nt_kernel<<<dim3(16, 24), 256, 0, stream>>>(qr, q_b_w, qbuf, SEQ, 3072, QRANK, QRANK, QRANK, 3072, 1.f);
    rope_apply_kernel<<<(SEQ * 16 * 32) / 256, 256, 0, stream>>>(qbuf, cos_t, sin_t, 16, 3072, 192, 128);

    // ckv = hidden @ kv_a_w^T ; rope k_pe; rmsnorm -> ckvn
    gemm_nt_kernel<<<dim3(16, 5), 256, 0, stream>>>(hidden, kv_a_w, ckv, SEQ, 576, HIDD, HIDD, HIDD, 576, 1.f);
    rope_apply_kernel<<<(SEQ * 32) / 256, 256, 0, stream>>>(ckv, cos_t, sin_t, 1, 576, 0, 512);
    rmsnorm_kernel<<<SEQ, 256, 0, stream>>>(ckv, kv_a_ln_w, ckvn, KVRANK, 576);

    // indexer q: iq = qr @ idx_wq_b_w^T ; rope [0:64] per head
    gemm_nt_kernel<<<dim3(16, 16), 256, 0, stream>>>(qr, idx_wq_b_w, iqb, SEQ, 2048, QRANK, QRANK, QRANK, 2048, 1.f);
    rope_apply_kernel<<<(SEQ * 16 * 32) / 256, 256, 0, stream>>>(iqb, cos_t, sin_t, 16, 2048, 128, 0);

    // indexer k: ik = rope(layernorm(hidden @ idx_wk_w^T))
    gemm_nt_kernel<<<dim3(16, 1), 256, 0, stream>>>(hidden, idx_wk_w, ikb, SEQ, IDIM, HIDD, HIDD, HIDD, IDIM, 1.f);
    layernorm_kernel<<<SEQ, 64, 0, stream>>>(ikb, idx_kn_w, idx_kn_b, ikb);
    rope_apply_kernel<<<(SEQ * 32) / 256, 256, 0, stream>>>(ikb, cos_t, sin_t, 1, 128, 0, 0);

    // iw = hidden @ idx_wproj_w^T * 0.25
    gemm_nt_kernel<<<dim3(16, 1), 256, 0, stream>>>(hidden, idx_wproj_w, iwb, SEQ, IHEAD, HIDD, HIDD, HIDD, IHEAD, 0.25f);

    // indexer scores + topk
    idx_scores_kernel<<<dim3(32, 32), 256, 0, stream>>>(iqb, ikb, iwb, scores);
    topk_kernel<<<SEQ, 1024, 0, stream>>>(scores, sel);

    // q absorption: qabs[q,h,:] = q_nope[q,h,:] @ Wk_h  (NN, K=128, N=512)
    gemm_batched_kernel<float, __hip_bfloat16, false><<<dim3(16, 4, 16), 256, 0, stream>>>(
        qbuf, kv_b_w, qabsb, SEQ, 512, 128, 3072, 512, 16 * 512,
        192L, 256L * 512L, 512L, 1.f);

    // absorbed sparse attention -> ocomp (normalized)
    attn_abs_kernel<<<SEQ, 256, 0, stream>>>(qabsb, qbuf, ckvn, ckv, sel, ocomp);

    // output projection: attno[q, h*128+d] = ocomp[q,h,:] @ Wv_h^T  (NT, K=512, N=128)
    gemm_batched_kernel<__hip_bfloat16, float, true><<<dim3(16, 1, 16), 256, 0, stream>>>(
        ocomp, kv_b_w + 128 * 512, attno, SEQ, 128, 512, 16 * 512, 512, 2048,
        512L, 256L * 512L, 128L, 1.f);

    // out = attno @ o_w^T
    gemm_nt_kernel<<<dim3(16, 16), 256, 0, stream>>>(attno, o_w, out, SEQ, HIDD, 2048, 2048, 2048, HIDD, 1.f);
}

// Round 3
// 3066.282 us; speedup vs baseline: 1.5648x; 1.3467x over previous
//
#include <hip/hip_runtime.h>
#include <hip/hip_bf16.h>
#include <math.h>

#define SEQ 2048
#define HIDD 2048
#define QRANK 1536
#define KVRANK 512
#define IHEAD 16
#define IDIM 128
#define TOPK 512
#define EPSF 1e-6f
#define SCALE_ATTN 0.07216878364870323f  /* 192^-0.5 */
#define KB 16

typedef __attribute__((ext_vector_type(8))) short short8v;
typedef __attribute__((ext_vector_type(4))) float f32x4;

__device__ inline unsigned short f2bf(float f) {
    unsigned u = __float_as_uint(f);
    unsigned r = (u + 0x7FFFu + ((u >> 16) & 1u)) >> 16;
    return (unsigned short)r;
}
__device__ inline float bf2f(unsigned short b) {
    return __uint_as_float(((unsigned)b) << 16);
}

// ---------------- RoPE cos/sin table ----------------
__global__ void rope_table_kernel(float* __restrict__ cos_t, float* __restrict__ sin_t) {
    int s = blockIdx.x;
    int i = threadIdx.x;  // 0..31
    double inv = pow(10000.0, -((double)(2 * i)) / 64.0);
    double f = (double)s * inv;
    cos_t[s * 32 + i] = (float)cos(f);
    sin_t[s * 32 + i] = (float)sin(f);
}

// ---------------- f32 -> bf16 convert ----------------
__global__ __launch_bounds__(256) void cvt_bf16_kernel(const float* __restrict__ in,
                                                       unsigned short* __restrict__ out, int n4) {
    for (int i = blockIdx.x * 256 + threadIdx.x; i < n4; i += gridDim.x * 256) {
        float4 v = ((const float4*)in)[i];
        ushort4 o;
        o.x = f2bf(v.x); o.y = f2bf(v.y); o.z = f2bf(v.z); o.w = f2bf(v.w);
        ((ushort4*)out)[i] = o;
    }
}

// ---------------- transpose k-absorb weights: wkt[h][n][d] = kv_b_w[h*256+d][n] ----------------
__global__ __launch_bounds__(256) void wkt_kernel(const float* __restrict__ kvb,
                                                  unsigned short* __restrict__ wkt) {
    int o = blockIdx.x * 256 + threadIdx.x;  // 16*512*128 = 1048576
    int d = o & 127;
    int n = (o >> 7) & 511;
    int h = o >> 16;
    wkt[o] = f2bf(kvb[((size_t)(h * 256 + d)) * 512 + n]);
}

// ---------------- f32 VALU NT GEMM (exact path: qa, iq, ik, iw) ----------------
__global__ __launch_bounds__(256) void gemm_nt_kernel(
    const float* __restrict__ A, const float* __restrict__ B, float* __restrict__ C,
    int M, int N, int K, int lda, int ldb, int ldc, float alpha)
{
    __shared__ float As[128][17];
    __shared__ float Bs[128][17];
    int tid = threadIdx.x;
    int tx = tid & 15, ty = tid >> 4;
    int m0 = blockIdx.x * 128, n0 = blockIdx.y * 128;
    float acc[8][8] = {};
    for (int k0 = 0; k0 < K; k0 += 16) {
        __syncthreads();
#pragma unroll
        for (int r = 0; r < 2; ++r) {
            int idx = tid + r * 256;
            int row = idx >> 2, c4 = idx & 3;
            int gm = m0 + row;
            float4 va = make_float4(0.f, 0.f, 0.f, 0.f);
            if (gm < M) va = *(const float4*)(A + (size_t)gm * lda + k0 + c4 * 4);
            As[row][c4 * 4 + 0] = va.x; As[row][c4 * 4 + 1] = va.y;
            As[row][c4 * 4 + 2] = va.z; As[row][c4 * 4 + 3] = va.w;
            int gn = n0 + row;
            float4 vb = make_float4(0.f, 0.f, 0.f, 0.f);
            if (gn < N) vb = *(const float4*)(B + (size_t)gn * ldb + k0 + c4 * 4);
            Bs[row][c4 * 4 + 0] = vb.x; Bs[row][c4 * 4 + 1] = vb.y;
            Bs[row][c4 * 4 + 2] = vb.z; Bs[row][c4 * 4 + 3] = vb.w;
        }
        __syncthreads();
#pragma unroll
        for (int kk = 0; kk < 16; ++kk) {
            float a[8], b[8];
#pragma unroll
            for (int i = 0; i < 8; ++i) a[i] = As[ty + 16 * i][kk];
#pragma unroll
            for (int j = 0; j < 8; ++j) b[j] = Bs[tx + 16 * j][kk];
#pragma unroll
            for (int i = 0; i < 8; ++i)
#pragma unroll
                for (int j = 0; j < 8; ++j)
                    acc[i][j] += a[i] * b[j];
        }
    }
#pragma unroll
    for (int i = 0; i < 8; ++i) {
        int gm = m0 + ty + 16 * i;
        if (gm >= M) continue;
#pragma unroll
        for (int j = 0; j < 8; ++j) {
            int gn = n0 + tx + 16 * j;
            if (gn < N) C[(size_t)gm * ldc + gn] = alpha * acc[i][j];
        }
    }
}

// ---------------- bf16 MFMA NT GEMM, batched ----------------
// C[z][m][n] = sum_k A[z][m][k] * B[z][n][k];  TA in {unsigned short(bf16), float}, TC in {float, unsigned short(bf16)}
// M must be a multiple of 128; K multiple of 32; N edge handled by row-clamp + store guard.
template <typename TA, typename TC>
__global__ __launch_bounds__(256) void mfma_nt_kernel(
    const TA* __restrict__ A, const unsigned short* __restrict__ B, TC* __restrict__ C,
    int M, int N, int K, int lda, int ldb, int ldc, long ab, long bb, long cb)
{
    __shared__ __align__(16) unsigned short Asl[128 * 32];
    __shared__ __align__(16) unsigned short Bsl[128 * 32];
    int z = blockIdx.z;
    const TA* Az = A + (size_t)z * ab;
    const unsigned short* Bz = B + (size_t)z * bb;
    TC* Cz = C + (size_t)z * cb;
    int tid = threadIdx.x;
    int l = tid & 63, w = tid >> 6;
    int wr = w >> 1, wc = w & 1;
    int m0 = blockIdx.x * 128, n0 = blockIdx.y * 128;
    f32x4 acc[4][4] = {};

    for (int k0 = 0; k0 < K; k0 += 32) {
        __syncthreads();
#pragma unroll
        for (int i = 0; i < 2; ++i) {
            int idx = tid + i * 256;      // 0..511
            int r = idx >> 2, cc = idx & 3;
            int sw = cc ^ (r & 3);
            // A row r (M multiple of 128 -> no guard)
            {
                short8v d;
                const TA* src = Az + (size_t)(m0 + r) * lda + k0 + cc * 8;
                if constexpr (sizeof(TA) == 2) {
                    d = *(const short8v*)src;
                } else {
                    float4 f0 = *(const float4*)src;
                    float4 f1 = *(const float4*)(src + 4);
                    d[0] = (short)f2bf(f0.x); d[1] = (short)f2bf(f0.y);
                    d[2] = (short)f2bf(f0.z); d[3] = (short)f2bf(f0.w);
                    d[4] = (short)f2bf(f1.x); d[5] = (short)f2bf(f1.y);
                    d[6] = (short)f2bf(f1.z); d[7] = (short)f2bf(f1.w);
                }
                *(short8v*)&Asl[r * 32 + sw * 8] = d;
            }
            // B row r, clamped to N-1
            {
                int gb = n0 + r; if (gb > N - 1) gb = N - 1;
                short8v d = *(const short8v*)(Bz + (size_t)gb * ldb + k0 + cc * 8);
                *(short8v*)&Bsl[r * 32 + sw * 8] = d;
            }
        }
        __syncthreads();
        short8v av[4], bv[4];
#pragma unroll
        for (int mt = 0; mt < 4; ++mt) {
            int row = wr * 64 + mt * 16 + (l & 15);
            int ch = (l >> 4) ^ (row & 3);
            av[mt] = *(const short8v*)&Asl[row * 32 + ch * 8];
        }
#pragma unroll
        for (int nt = 0; nt < 4; ++nt) {
            int row = wc * 64 + nt * 16 + (l & 15);
            int ch = (l >> 4) ^ (row & 3);
            bv[nt] = *(const short8v*)&Bsl[row * 32 + ch * 8];
        }
#pragma unroll
        for (int mt = 0; mt < 4; ++mt)
#pragma unroll
            for (int nt = 0; nt < 4; ++nt)
                acc[mt][nt] = __builtin_amdgcn_mfma_f32_16x16x32_bf16(av[mt], bv[nt], acc[mt][nt], 0, 0, 0);
    }
#pragma unroll
    for (int mt = 0; mt < 4; ++mt) {
#pragma unroll
        for (int nt = 0; nt < 4; ++nt) {
#pragma unroll
            for (int i = 0; i < 4; ++i) {
                int gm = m0 + wr * 64 + mt * 16 + (l >> 4) * 4 + i;
                int gn = n0 + wc * 64 + nt * 16 + (l & 15);
                if (gn < N) {
                    float v = acc[mt][nt][i];
                    if constexpr (sizeof(TC) == 4) Cz[(size_t)gm * ldc + gn] = v;
                    else Cz[(size_t)gm * ldc + gn] = f2bf(v);
                }
            }
        }
    }
}

// ---------------- RMSNorm, optional bf16 secondary output ----------------
__global__ __launch_bounds__(256) void rmsnorm_kernel(
    const float* __restrict__ in, const float* __restrict__ w, float* __restrict__ out,
    unsigned short* __restrict__ bf_out, int n, int in_stride)
{
    int row = blockIdx.x, tid = threadIdx.x;
    const float* x = in + (size_t)row * in_stride;
    float4 v[2];
    int cnt = 0;
    float ss = 0.f;
    int nf4 = n >> 2;
    for (int i = tid; i < nf4; i += 256) {
        float4 t = *(const float4*)(x + i * 4);
        v[cnt++] = t;
        ss += t.x * t.x + t.y * t.y + t.z * t.z + t.w * t.w;
    }
#pragma unroll
    for (int m = 32; m; m >>= 1) ss += __shfl_xor(ss, m);
    __shared__ float red[8];
    int wid = tid >> 6;
    if ((tid & 63) == 0) red[wid] = ss;
    __syncthreads();
    if (tid == 0) {
        float s = red[0] + red[1] + red[2] + red[3];
        red[4] = rsqrtf(s / (float)n + EPSF);
    }
    __syncthreads();
    float scale = red[4];
    cnt = 0;
    for (int i = tid; i < nf4; i += 256) {
        float4 t = v[cnt++];
        float4 wv = *(const float4*)(w + i * 4);
        float4 o;
        o.x = t.x * scale * wv.x; o.y = t.y * scale * wv.y;
        o.z = t.z * scale * wv.z; o.w = t.w * scale * wv.w;
        *(float4*)(out + (size_t)row * n + i * 4) = o;
        if (bf_out) {
            ushort4 ob;
            ob.x = f2bf(o.x); ob.y = f2bf(o.y); ob.z = f2bf(o.z); ob.w = f2bf(o.w);
            *(ushort4*)(bf_out + (size_t)row * n + i * 4) = ob;
        }
    }
}

// ---------------- LayerNorm (row length 128) ----------------
__global__ __launch_bounds__(64) void layernorm_kernel(
    const float* __restrict__ in, const float* __restrict__ w, const float* __restrict__ b,
    float* __restrict__ out)
{
    int row = blockIdx.x, tid = threadIdx.x;
    const float* x = in + (size_t)row * 128;
    float x0 = x[tid], x1 = x[tid + 64];
    float s = x0 + x1, ss = x0 * x0 + x1 * x1;
#pragma unroll
    for (int m = 32; m; m >>= 1) { s += __shfl_xor(s, m); ss += __shfl_xor(ss, m); }
    float mean = s * (1.f / 128.f);
    float var = ss * (1.f / 128.f) - mean * mean;
    float r = rsqrtf(var + EPSF);
    out[(size_t)row * 128 + tid] = (x0 - mean) * r * w[tid] + b[tid];
    out[(size_t)row * 128 + tid + 64] = (x1 - mean) * r * w[tid + 64] + b[tid + 64];
}

// ---------------- RoPE in-place ----------------
__global__ void rope_apply_kernel(
    float* __restrict__ x, const float* __restrict__ cos_t, const float* __restrict__ sin_t,
    int heads, int row_stride, int head_stride, int offset)
{
    int t = blockIdx.x * blockDim.x + threadIdx.x;
    int i = t & 31;
    int hh = (t >> 5) % heads;
    int r = t / (32 * heads);
    if (r >= SEQ) return;
    float* p = x + (size_t)r * row_stride + hh * head_stride + offset;
    float c = cos_t[r * 32 + i], s = sin_t[r * 32 + i];
    float x1 = p[i], x2 = p[i + 32];
    p[i] = x1 * c - x2 * s;
    p[i + 32] = x2 * c + x1 * s;
}

// ---------------- indexer scores (exact f32) ----------------
__global__ __launch_bounds__(256) void idx_scores_kernel(
    const float* __restrict__ iq, const float* __restrict__ ik,
    const float* __restrict__ iw, float* __restrict__ scores)
{
    int q0 = blockIdx.x * 64, k0 = blockIdx.y * 64;
    int tid = threadIdx.x;
    int tx = tid & 15, ty = tid >> 4;
    if (k0 > q0 + 63) {
        for (int t = tid; t < 64 * 64; t += 256) {
            int r = t >> 6, c = t & 63;
            scores[(size_t)(q0 + r) * SEQ + k0 + c] = -INFINITY;
        }
        return;
    }
    __shared__ float iks[64][132];
    __shared__ float iqs[64][132];
    __shared__ float iws[64][16];
    for (int t = tid; t < 64 * 32; t += 256) {
        int r = t >> 5, c4 = t & 31;
        *(float4*)&iks[r][c4 * 4] = *(const float4*)(ik + (size_t)(k0 + r) * 128 + c4 * 4);
    }
    for (int t = tid; t < 64 * 16; t += 256) {
        int r = t >> 4, c = t & 15;
        iws[r][c] = iw[(size_t)(q0 + r) * 16 + c];
    }
    float acc[4][4] = {};
    for (int h = 0; h < 16; ++h) {
        __syncthreads();
        for (int t = tid; t < 64 * 32; t += 256) {
            int r = t >> 5, c4 = t & 31;
            *(float4*)&iqs[r][c4 * 4] = *(const float4*)(iq + ((size_t)(q0 + r) * 16 + h) * 128 + c4 * 4);
        }
        __syncthreads();
        float dot[4][4] = {};
        for (int d = 0; d < 128; ++d) {
            float a[4], b[4];
#pragma unroll
            for (int i = 0; i < 4; ++i) a[i] = iqs[ty + 16 * i][d];
#pragma unroll
            for (int j = 0; j < 4; ++j) b[j] = iks[tx + 16 * j][d];
#pragma unroll
            for (int i = 0; i < 4; ++i)
#pragma unroll
                for (int j = 0; j < 4; ++j)
                    dot[i][j] += a[i] * b[j];
        }
#pragma unroll
        for (int i = 0; i < 4; ++i)
#pragma unroll
            for (int j = 0; j < 4; ++j)
                acc[i][j] += iws[ty + 16 * i][h] * fmaxf(dot[i][j], 0.f);
    }
#pragma unroll
    for (int i = 0; i < 4; ++i) {
        int q = q0 + ty + 16 * i;
#pragma unroll
        for (int j = 0; j < 4; ++j) {
            int k = k0 + tx + 16 * j;
            scores[(size_t)q * SEQ + k] = (k <= q) ? acc[i][j] : -INFINITY;
        }
    }
}

// ---------------- top-512 per row via bitonic sort ----------------
__global__ __launch_bounds__(1024) void topk_kernel(
    const float* __restrict__ scores, int* __restrict__ sel)
{
    int qi = blockIdx.x, tid = threadIdx.x;
    __shared__ unsigned long long keys[2048];
    const float* srow = scores + (size_t)qi * SEQ;
#pragma unroll
    for (int r = 0; r < 2; ++r) {
        int k = tid + r * 1024;
        unsigned u = __float_as_uint(srow[k]);
        unsigned mv = (u & 0x80000000u) ? ~u : (u | 0x80000000u);
        keys[k] = ((unsigned long long)mv << 32) | (unsigned)(2047 - k);
    }
    for (int ksz = 2; ksz <= 2048; ksz <<= 1) {
        for (int j = ksz >> 1; j > 0; j >>= 1) {
            __syncthreads();
#pragma unroll 1
            for (int r = 0; r < 2; ++r) {
                int i = tid + r * 1024;
                int ixj = i ^ j;
                if (ixj > i) {
                    unsigned long long a = keys[i], b = keys[ixj];
                    bool dir = ((i & ksz) == 0);
                    if ((a < b) == dir) { keys[i] = b; keys[ixj] = a; }
                }
            }
        }
    }
    __syncthreads();
    if (tid < TOPK) {
        int k = 2047 - (int)(keys[tid] & 0xFFFFFFFFu);
        sel[(size_t)qi * TOPK + tid] = (tid <= qi) ? k : -1;
    }
}

// ---------------- absorbed sparse attention ----------------
__global__ __launch_bounds__(256) void attn_abs_kernel(
    const __hip_bfloat16* __restrict__ qabs,  // (S,16,512) bf16
    const float* __restrict__ qsrc,           // qbuf (S,16,192), qpe at +128
    const float* __restrict__ ckvn,           // (S,512)
    const float* __restrict__ ckv,            // (S,576), kpe at +512
    const int* __restrict__ sel,              // (S,512)
    __hip_bfloat16* __restrict__ ocomp)       // (S,16,512) bf16, normalized
{
    int qi = blockIdx.x;
    int tid = threadIdx.x;
    int h = tid >> 4, g = tid & 15;
    __shared__ float cs[KB][512];
    __shared__ float ps[KB][64];
    __shared__ int selb[KB];

    float4 qa[8];
    const unsigned short* qrow = (const unsigned short*)(qabs + ((size_t)qi * 16 + h) * 512);
#pragma unroll
    for (int j = 0; j < 8; ++j) {
        int r = g * 32 + ((j + g) & 7) * 4;
        ushort4 u = *(const ushort4*)(qrow + r);
        qa[j].x = bf2f(u.x); qa[j].y = bf2f(u.y); qa[j].z = bf2f(u.z); qa[j].w = bf2f(u.w);
    }
    float4 qp = *(const float4*)(qsrc + (size_t)qi * 3072 + h * 192 + 128 + g * 4);

    float m = -1e30f, l = 0.f;
    float4 oc[8] = {};
    int nv = min(TOPK, qi + 1);

    for (int j0 = 0; j0 < nv; j0 += KB) {
        int nb = min(KB, nv - j0);
        __syncthreads();
        if (tid < nb) selb[tid] = sel[(size_t)qi * TOPK + j0 + tid];
        __syncthreads();
        for (int t = tid; t < nb * 128; t += 256) {
            int key = t >> 7, f4 = t & 127;
            ((float4*)cs[key])[f4] = ((const float4*)(ckvn + (size_t)selb[key] * 512))[f4];
        }
        for (int t = tid; t < nb * 16; t += 256) {
            int key = t >> 4, f4 = t & 15;
            ((float4*)ps[key])[f4] = ((const float4*)(ckv + (size_t)selb[key] * 576 + 512))[f4];
        }
        __syncthreads();
        for (int kk = 0; kk < nb; ++kk) {
            float4 ck[8];
            const float* crow = cs[kk];
#pragma unroll
            for (int j = 0; j < 8; ++j) {
                int r = g * 32 + ((j + g) & 7) * 4;
                ck[j] = *(const float4*)(crow + r);
            }
            float4 pe = *(const float4*)(ps[kk] + g * 4);
            float part = qp.x * pe.x + qp.y * pe.y + qp.z * pe.z + qp.w * pe.w;
#pragma unroll
            for (int j = 0; j < 8; ++j)
                part += qa[j].x * ck[j].x + qa[j].y * ck[j].y + qa[j].z * ck[j].z + qa[j].w * ck[j].w;
            part += __shfl_xor(part, 1);
            part += __shfl_xor(part, 2);
            part += __shfl_xor(part, 4);
            part += __shfl_xor(part, 8);
            float sc = part * SCALE_ATTN;
            if (sc - m > 8.f) {
                float so = __expf(m - sc);
                l *= so;
#pragma unroll
                for (int j = 0; j < 8; ++j) {
                    oc[j].x *= so; oc[j].y *= so; oc[j].z *= so; oc[j].w *= so;
                }
                m = sc;
            }
            float p = __expf(sc - m);
            l += p;
#pragma unroll
            for (int j = 0; j < 8; ++j) {
                oc[j].x += p * ck[j].x; oc[j].y += p * ck[j].y;
                oc[j].z += p * ck[j].z; oc[j].w += p * ck[j].w;
            }
        }
    }
    float invl = 1.f / l;
    unsigned short* orow = (unsigned short*)(ocomp + ((size_t)qi * 16 + h) * 512);
#pragma unroll
    for (int j = 0; j < 8; ++j) {
        int r = g * 32 + ((j + g) & 7) * 4;
        ushort4 o;
        o.x = f2bf(oc[j].x * invl); o.y = f2bf(oc[j].y * invl);
        o.z = f2bf(oc[j].z * invl); o.w = f2bf(oc[j].w * invl);
        *(ushort4*)(orow + r) = o;
    }
}

// ---------------- launcher ----------------
extern "C" void kernel_launch(void* const* d_in, const int* in_sizes, int n_in,
                              void* d_out, int out_size, void* d_ws, size_t ws_size,
                              hipStream_t stream) {
    (void)in_sizes; (void)n_in; (void)out_size; (void)ws_size;
    const float* hidden      = (const float*)d_in[0];
    const float* q_a_w       = (const float*)d_in[1];
    const float* q_a_ln_w    = (const float*)d_in[2];
    const float* q_b_w       = (const float*)d_in[3];
    const float* kv_a_w      = (const float*)d_in[4];
    const float* kv_a_ln_w   = (const float*)d_in[5];
    const float* kv_b_w      = (const float*)d_in[6];
    const float* o_w         = (const float*)d_in[7];
    const float* idx_wq_b_w  = (const float*)d_in[8];
    const float* idx_wk_w    = (const float*)d_in[9];
    const float* idx_kn_w    = (const float*)d_in[10];
    const float* idx_kn_b    = (const float*)d_in[11];
    const float* idx_wproj_w = (const float*)d_in[12];
    float* out = (float*)d_out;

    char* ws = (char*)d_ws;
    size_t off = 0;
    auto alloc = [&](size_t nbytes) -> void* {
        void* p = ws + off;
        off = (off + nbytes + 255) & ~(size_t)255;
        return p;
    };
    // persistent
    float* cos_t = (float*)alloc((size_t)SEQ * 32 * 4);
    float* sin_t = (float*)alloc((size_t)SEQ * 32 * 4);
    float* qbuf  = (float*)alloc((size_t)SEQ * 3072 * 4);
    float* ckv   = (float*)alloc((size_t)SEQ * 576 * 4);
    float* ckvn  = (float*)alloc((size_t)SEQ * KVRANK * 4);
    int*   sel   = (int*)alloc((size_t)SEQ * TOPK * 4);
    unsigned short* attno_bf = (unsigned short*)alloc((size_t)SEQ * 2048 * 2);
    unsigned short* qr_bf    = (unsigned short*)alloc((size_t)SEQ * QRANK * 2);
    unsigned short* q_b_bf   = (unsigned short*)alloc((size_t)3072 * QRANK * 2);
    unsigned short* kv_a_bf  = (unsigned short*)alloc((size_t)576 * HIDD * 2);
    unsigned short* o_w_bf   = (unsigned short*)alloc((size_t)HIDD * 2048 * 2);
    unsigned short* kv_b_bf  = (unsigned short*)alloc((size_t)4096 * 512 * 2);
    unsigned short* wkt      = (unsigned short*)alloc((size_t)16 * 512 * 128 * 2);
    size_t mark = off;
    // transients (dead after topk)
    float* qr    = (float*)alloc((size_t)SEQ * QRANK * 4);
    float* iqb   = (float*)alloc((size_t)SEQ * 2048 * 4);
    float* ikb   = (float*)alloc((size_t)SEQ * 128 * 4);
    float* iwb   = (float*)alloc((size_t)SEQ * 16 * 4);
    float* scores = (float*)alloc((size_t)SEQ * SEQ * 4);
    // overlay region (alive after topk)
    off = mark;
    __hip_bfloat16* qabsb = (__hip_bfloat16*)alloc((size_t)SEQ * 16 * 512 * 2);
    __hip_bfloat16* ocomp = (__hip_bfloat16*)alloc((size_t)SEQ * 16 * 512 * 2);

    rope_table_kernel<<<dim3(SEQ), dim3(32), 0, stream>>>(cos_t, sin_t);

    // weight converts
    cvt_bf16_kernel<<<1024, 256, 0, stream>>>(q_b_w, q_b_bf, 3072 * QRANK / 4);
    cvt_bf16_kernel<<<1024, 256, 0, stream>>>(kv_a_w, kv_a_bf, 576 * HIDD / 4);
    cvt_bf16_kernel<<<1024, 256, 0, stream>>>(o_w, o_w_bf, HIDD * 2048 / 4);
    cvt_bf16_kernel<<<1024, 256, 0, stream>>>(kv_b_w, kv_b_bf, 4096 * 512 / 4);
    wkt_kernel<<<4096, 256, 0, stream>>>(kv_b_w, wkt);

    // qr = rmsnorm(hidden @ q_a_w^T)  (exact f32 path; dual f32+bf16 out)
    gemm_nt_kernel<<<dim3(16, 12), 256, 0, stream>>>(hidden, q_a_w, qr, SEQ, QRANK, HIDD, HIDD, HIDD, QRANK, 1.f);
    rmsnorm_kernel<<<SEQ, 256, 0, stream>>>(qr, q_a_ln_w, qr, qr_bf, QRANK, QRANK);

    // q = qr @ q_b_w^T  (bf16 MFMA) ; rope on [128:192] per head
    mfma_nt_kernel<unsigned short, float><<<dim3(16, 24, 1), 256, 0, stream>>>(
        qr_bf, q_b_bf, qbuf, SEQ, 3072, QRANK, QRANK, QRANK, 3072, 0L, 0L, 0L);
    rope_apply_kernel<<<(SEQ * 16 * 32) / 256, 256, 0, stream>>>(qbuf, cos_t, sin_t, 16, 3072, 192, 128);

    // ckv = hidden @ kv_a_w^T (MFMA, f32 A converted in staging); rope kpe; rmsnorm -> ckvn
    mfma_nt_kernel<float, float><<<dim3(16, 5, 1), 256, 0, stream>>>(
        hidden, kv_a_bf, ckv, SEQ, 576, HIDD, HIDD, HIDD, 576, 0L, 0L, 0L);
    rope_apply_kernel<<<(SEQ * 32) / 256, 256, 0, stream>>>(ckv, cos_t, sin_t, 1, 576, 0, 512);
    rmsnorm_kernel<<<SEQ, 256, 0, stream>>>(ckv, kv_a_ln_w, ckvn, nullptr, KVRANK, 576);

    // indexer path: exact f32
    gemm_nt_kernel<<<dim3(16, 16), 256, 0, stream>>>(qr, idx_wq_b_w, iqb, SEQ, 2048, QRANK, QRANK, QRANK, 2048, 1.f);
    rope_apply_kernel<<<(SEQ * 16 * 32) / 256, 256, 0, stream>>>(iqb, cos_t, sin_t, 16, 2048, 128, 0);
    gemm_nt_kernel<<<dim3(16, 1), 256, 0, stream>>>(hidden, idx_wk_w, ikb, SEQ, IDIM, HIDD, HIDD, HIDD, IDIM, 1.f);
    layernorm_kernel<<<SEQ, 64, 0, stream>>>(ikb, idx_kn_w, idx_kn_b, ikb);
    rope_apply_kernel<<<(SEQ * 32) / 256, 256, 0, stream>>>(ikb, cos_t, sin_t, 1, 128, 0, 0);
    gemm_nt_kernel<<<dim3(16, 1), 256, 0, stream>>>(hidden, idx_wproj_w, iwb, SEQ, IHEAD, HIDD, HIDD, HIDD, IHEAD, 0.25f);
    idx_scores_kernel<<<dim3(32, 32), 256, 0, stream>>>(iqb, ikb, iwb, scores);
    topk_kernel<<<SEQ, 1024, 0, stream>>>(scores, sel);

    // q absorption (bf16 MFMA, batched per head): qabs[q,h,n] = sum_d qnope[q,h,d] * wkt[h,n,d]
    mfma_nt_kernel<float, unsigned short><<<dim3(16, 4, 16), 256, 0, stream>>>(
        qbuf, wkt, (unsigned short*)qabsb, SEQ, 512, 128, 3072, 128, 16 * 512,
        192L, 512L * 128L, 512L);

    // absorbed sparse attention -> ocomp (normalized)
    attn_abs_kernel<<<SEQ, 256, 0, stream>>>(qabsb, qbuf, ckvn, ckv, sel, ocomp);

    // output projection (bf16 MFMA, batched): attno[q, h*128+n] = ocomp[q,h,:] . kv_b[h*256+128+n,:]
    mfma_nt_kernel<unsigned short, unsigned short><<<dim3(16, 1, 16), 256, 0, stream>>>(
        (const unsigned short*)ocomp, kv_b_bf + (size_t)128 * 512, attno_bf, SEQ, 128, 512,
        16 * 512, 512, 2048, 512L, 256L * 512L, 128L);

    // out = attno @ o_w^T (bf16 MFMA)
    mfma_nt_kernel<unsigned short, float><<<dim3(16, 16, 1), 256, 0, stream>>>(
        attno_bf, o_w_bf, out, SEQ, HIDD, 2048, 2048, 2048, HIDD, 0L, 0L, 0L);
}

// Round 4
// 2507.211 us; speedup vs baseline: 1.9138x; 1.2230x over previous
//
#include <hip/hip_runtime.h>
#include <hip/hip_bf16.h>
#include <math.h>

#define SEQ 2048
#define HIDD 2048
#define QRANK 1536
#define KVRANK 512
#define IHEAD 16
#define IDIM 128
#define TOPK 512
#define EPSF 1e-6f
#define SCALE_ATTN 0.07216878364870323f  /* 192^-0.5 */

typedef __attribute__((ext_vector_type(8))) short short8v;
typedef __attribute__((ext_vector_type(4))) float f32x4;

__device__ inline unsigned short f2bf(float f) {
    unsigned u = __float_as_uint(f);
    unsigned r = (u + 0x7FFFu + ((u >> 16) & 1u)) >> 16;
    return (unsigned short)r;
}
__device__ inline float bf2f(unsigned short b) {
    return __uint_as_float(((unsigned)b) << 16);
}

// ---------------- RoPE cos/sin table ----------------
__global__ void rope_table_kernel(float* __restrict__ cos_t, float* __restrict__ sin_t) {
    int s = blockIdx.x;
    int i = threadIdx.x;  // 0..31
    double inv = pow(10000.0, -((double)(2 * i)) / 64.0);
    double f = (double)s * inv;
    cos_t[s * 32 + i] = (float)cos(f);
    sin_t[s * 32 + i] = (float)sin(f);
}

// ---------------- f32 -> bf16 convert ----------------
__global__ __launch_bounds__(256) void cvt_bf16_kernel(const float* __restrict__ in,
                                                       unsigned short* __restrict__ out, int n4) {
    for (int i = blockIdx.x * 256 + threadIdx.x; i < n4; i += gridDim.x * 256) {
        float4 v = ((const float4*)in)[i];
        ushort4 o;
        o.x = f2bf(v.x); o.y = f2bf(v.y); o.z = f2bf(v.z); o.w = f2bf(v.w);
        ((ushort4*)out)[i] = o;
    }
}

// ---------------- transpose k-absorb weights: wkt[h][n][d] = kv_b_w[h*256+d][n] ----------------
__global__ __launch_bounds__(256) void wkt_kernel(const float* __restrict__ kvb,
                                                  unsigned short* __restrict__ wkt) {
    int o = blockIdx.x * 256 + threadIdx.x;  // 16*512*128 = 1048576
    int d = o & 127;
    int n = (o >> 7) & 511;
    int h = o >> 16;
    wkt[o] = f2bf(kvb[((size_t)(h * 256 + d)) * 512 + n]);
}

// ---------------- kh_g[s][0:512]=bf16(ckvn[s]); [512:576]=bf16(roped kpe) ----------------
__global__ __launch_bounds__(256) void khg_kernel(const float* __restrict__ ckvn,
                                                  const float* __restrict__ ckv,
                                                  unsigned short* __restrict__ khg) {
    int s = blockIdx.x;
    for (int i = threadIdx.x; i < 576; i += 256) {
        float v = (i < 512) ? ckvn[(size_t)s * 512 + i] : ckv[(size_t)s * 576 + i];
        khg[(size_t)s * 576 + i] = f2bf(v);
    }
}

// ---------------- f32 VALU NT GEMM (exact path: qa, iq, ik, iw) ----------------
__global__ __launch_bounds__(256) void gemm_nt_kernel(
    const float* __restrict__ A, const float* __restrict__ B, float* __restrict__ C,
    int M, int N, int K, int lda, int ldb, int ldc, float alpha)
{
    __shared__ float As[128][17];
    __shared__ float Bs[128][17];
    int tid = threadIdx.x;
    int tx = tid & 15, ty = tid >> 4;
    int m0 = blockIdx.x * 128, n0 = blockIdx.y * 128;
    float acc[8][8] = {};
    for (int k0 = 0; k0 < K; k0 += 16) {
        __syncthreads();
#pragma unroll
        for (int r = 0; r < 2; ++r) {
            int idx = tid + r * 256;
            int row = idx >> 2, c4 = idx & 3;
            int gm = m0 + row;
            float4 va = make_float4(0.f, 0.f, 0.f, 0.f);
            if (gm < M) va = *(const float4*)(A + (size_t)gm * lda + k0 + c4 * 4);
            As[row][c4 * 4 + 0] = va.x; As[row][c4 * 4 + 1] = va.y;
            As[row][c4 * 4 + 2] = va.z; As[row][c4 * 4 + 3] = va.w;
            int gn = n0 + row;
            float4 vb = make_float4(0.f, 0.f, 0.f, 0.f);
            if (gn < N) vb = *(const float4*)(B + (size_t)gn * ldb + k0 + c4 * 4);
            Bs[row][c4 * 4 + 0] = vb.x; Bs[row][c4 * 4 + 1] = vb.y;
            Bs[row][c4 * 4 + 2] = vb.z; Bs[row][c4 * 4 + 3] = vb.w;
        }
        __syncthreads();
#pragma unroll
        for (int kk = 0; kk < 16; ++kk) {
            float a[8], b[8];
#pragma unroll
            for (int i = 0; i < 8; ++i) a[i] = As[ty + 16 * i][kk];
#pragma unroll
            for (int j = 0; j < 8; ++j) b[j] = Bs[tx + 16 * j][kk];
#pragma unroll
            for (int i = 0; i < 8; ++i)
#pragma unroll
                for (int j = 0; j < 8; ++j)
                    acc[i][j] += a[i] * b[j];
        }
    }
#pragma unroll
    for (int i = 0; i < 8; ++i) {
        int gm = m0 + ty + 16 * i;
        if (gm >= M) continue;
#pragma unroll
        for (int j = 0; j < 8; ++j) {
            int gn = n0 + tx + 16 * j;
            if (gn < N) C[(size_t)gm * ldc + gn] = alpha * acc[i][j];
        }
    }
}

// ---------------- bf16 MFMA NT GEMM, batched ----------------
template <typename TA, typename TC>
__global__ __launch_bounds__(256) void mfma_nt_kernel(
    const TA* __restrict__ A, const unsigned short* __restrict__ B, TC* __restrict__ C,
    int M, int N, int K, int lda, int ldb, int ldc, long ab, long bb, long cb)
{
    __shared__ __align__(16) unsigned short Asl[128 * 32];
    __shared__ __align__(16) unsigned short Bsl[128 * 32];
    int z = blockIdx.z;
    const TA* Az = A + (size_t)z * ab;
    const unsigned short* Bz = B + (size_t)z * bb;
    TC* Cz = C + (size_t)z * cb;
    int tid = threadIdx.x;
    int l = tid & 63, w = tid >> 6;
    int wr = w >> 1, wc = w & 1;
    int m0 = blockIdx.x * 128, n0 = blockIdx.y * 128;
    f32x4 acc[4][4] = {};

    for (int k0 = 0; k0 < K; k0 += 32) {
        __syncthreads();
#pragma unroll
        for (int i = 0; i < 2; ++i) {
            int idx = tid + i * 256;
            int r = idx >> 2, cc = idx & 3;
            int sw = cc ^ (r & 3);
            {
                short8v d;
                const TA* src = Az + (size_t)(m0 + r) * lda + k0 + cc * 8;
                if constexpr (sizeof(TA) == 2) {
                    d = *(const short8v*)src;
                } else {
                    float4 f0 = *(const float4*)src;
                    float4 f1 = *(const float4*)(src + 4);
                    d[0] = (short)f2bf(f0.x); d[1] = (short)f2bf(f0.y);
                    d[2] = (short)f2bf(f0.z); d[3] = (short)f2bf(f0.w);
                    d[4] = (short)f2bf(f1.x); d[5] = (short)f2bf(f1.y);
                    d[6] = (short)f2bf(f1.z); d[7] = (short)f2bf(f1.w);
                }
                *(short8v*)&Asl[r * 32 + sw * 8] = d;
            }
            {
                int gb = n0 + r; if (gb > N - 1) gb = N - 1;
                short8v d = *(const short8v*)(Bz + (size_t)gb * ldb + k0 + cc * 8);
                *(short8v*)&Bsl[r * 32 + sw * 8] = d;
            }
        }
        __syncthreads();
        short8v av[4], bv[4];
#pragma unroll
        for (int mt = 0; mt < 4; ++mt) {
            int row = wr * 64 + mt * 16 + (l & 15);
            int ch = (l >> 4) ^ (row & 3);
            av[mt] = *(const short8v*)&Asl[row * 32 + ch * 8];
        }
#pragma unroll
        for (int nt = 0; nt < 4; ++nt) {
            int row = wc * 64 + nt * 16 + (l & 15);
            int ch = (l >> 4) ^ (row & 3);
            bv[nt] = *(const short8v*)&Bsl[row * 32 + ch * 8];
        }
#pragma unroll
        for (int mt = 0; mt < 4; ++mt)
#pragma unroll
            for (int nt = 0; nt < 4; ++nt)
                acc[mt][nt] = __builtin_amdgcn_mfma_f32_16x16x32_bf16(av[mt], bv[nt], acc[mt][nt], 0, 0, 0);
    }
#pragma unroll
    for (int mt = 0; mt < 4; ++mt) {
#pragma unroll
        for (int nt = 0; nt < 4; ++nt) {
#pragma unroll
            for (int i = 0; i < 4; ++i) {
                int gm = m0 + wr * 64 + mt * 16 + (l >> 4) * 4 + i;
                int gn = n0 + wc * 64 + nt * 16 + (l & 15);
                if (gn < N) {
                    float v = acc[mt][nt][i];
                    if constexpr (sizeof(TC) == 4) Cz[(size_t)gm * ldc + gn] = v;
                    else Cz[(size_t)gm * ldc + gn] = f2bf(v);
                }
            }
        }
    }
}

// ---------------- RMSNorm, optional bf16 secondary output ----------------
__global__ __launch_bounds__(256) void rmsnorm_kernel(
    const float* __restrict__ in, const float* __restrict__ w, float* __restrict__ out,
    unsigned short* __restrict__ bf_out, int n, int in_stride)
{
    int row = blockIdx.x, tid = threadIdx.x;
    const float* x = in + (size_t)row * in_stride;
    float4 v[2];
    int cnt = 0;
    float ss = 0.f;
    int nf4 = n >> 2;
    for (int i = tid; i < nf4; i += 256) {
        float4 t = *(const float4*)(x + i * 4);
        v[cnt++] = t;
        ss += t.x * t.x + t.y * t.y + t.z * t.z + t.w * t.w;
    }
#pragma unroll
    for (int m = 32; m; m >>= 1) ss += __shfl_xor(ss, m);
    __shared__ float red[8];
    int wid = tid >> 6;
    if ((tid & 63) == 0) red[wid] = ss;
    __syncthreads();
    if (tid == 0) {
        float s = red[0] + red[1] + red[2] + red[3];
        red[4] = rsqrtf(s / (float)n + EPSF);
    }
    __syncthreads();
    float scale = red[4];
    cnt = 0;
    for (int i = tid; i < nf4; i += 256) {
        float4 t = v[cnt++];
        float4 wv = *(const float4*)(w + i * 4);
        float4 o;
        o.x = t.x * scale * wv.x; o.y = t.y * scale * wv.y;
        o.z = t.z * scale * wv.z; o.w = t.w * scale * wv.w;
        *(float4*)(out + (size_t)row * n + i * 4) = o;
        if (bf_out) {
            ushort4 ob;
            ob.x = f2bf(o.x); ob.y = f2bf(o.y); ob.z = f2bf(o.z); ob.w = f2bf(o.w);
            *(ushort4*)(bf_out + (size_t)row * n + i * 4) = ob;
        }
    }
}

// ---------------- LayerNorm (row length 128) ----------------
__global__ __launch_bounds__(64) void layernorm_kernel(
    const float* __restrict__ in, const float* __restrict__ w, const float* __restrict__ b,
    float* __restrict__ out)
{
    int row = blockIdx.x, tid = threadIdx.x;
    const float* x = in + (size_t)row * 128;
    float x0 = x[tid], x1 = x[tid + 64];
    float s = x0 + x1, ss = x0 * x0 + x1 * x1;
#pragma unroll
    for (int m = 32; m; m >>= 1) { s += __shfl_xor(s, m); ss += __shfl_xor(ss, m); }
    float mean = s * (1.f / 128.f);
    float var = ss * (1.f / 128.f) - mean * mean;
    float r = rsqrtf(var + EPSF);
    out[(size_t)row * 128 + tid] = (x0 - mean) * r * w[tid] + b[tid];
    out[(size_t)row * 128 + tid + 64] = (x1 - mean) * r * w[tid + 64] + b[tid + 64];
}

// ---------------- RoPE in-place ----------------
__global__ void rope_apply_kernel(
    float* __restrict__ x, const float* __restrict__ cos_t, const float* __restrict__ sin_t,
    int heads, int row_stride, int head_stride, int offset)
{
    int t = blockIdx.x * blockDim.x + threadIdx.x;
    int i = t & 31;
    int hh = (t >> 5) % heads;
    int r = t / (32 * heads);
    if (r >= SEQ) return;
    float* p = x + (size_t)r * row_stride + hh * head_stride + offset;
    float c = cos_t[r * 32 + i], s = sin_t[r * 32 + i];
    float x1 = p[i], x2 = p[i + 32];
    p[i] = x1 * c - x2 * s;
    p[i + 32] = x2 * c + x1 * s;
}

// ---------------- indexer scores (exact f32) ----------------
__global__ __launch_bounds__(256) void idx_scores_kernel(
    const float* __restrict__ iq, const float* __restrict__ ik,
    const float* __restrict__ iw, float* __restrict__ scores)
{
    int q0 = blockIdx.x * 64, k0 = blockIdx.y * 64;
    int tid = threadIdx.x;
    int tx = tid & 15, ty = tid >> 4;
    if (k0 > q0 + 63) {
        for (int t = tid; t < 64 * 64; t += 256) {
            int r = t >> 6, c = t & 63;
            scores[(size_t)(q0 + r) * SEQ + k0 + c] = -INFINITY;
        }
        return;
    }
    __shared__ float iks[64][132];
    __shared__ float iqs[64][132];
    __shared__ float iws[64][16];
    for (int t = tid; t < 64 * 32; t += 256) {
        int r = t >> 5, c4 = t & 31;
        *(float4*)&iks[r][c4 * 4] = *(const float4*)(ik + (size_t)(k0 + r) * 128 + c4 * 4);
    }
    for (int t = tid; t < 64 * 16; t += 256) {
        int r = t >> 4, c = t & 15;
        iws[r][c] = iw[(size_t)(q0 + r) * 16 + c];
    }
    float acc[4][4] = {};
    for (int h = 0; h < 16; ++h) {
        __syncthreads();
        for (int t = tid; t < 64 * 32; t += 256) {
            int r = t >> 5, c4 = t & 31;
            *(float4*)&iqs[r][c4 * 4] = *(const float4*)(iq + ((size_t)(q0 + r) * 16 + h) * 128 + c4 * 4);
        }
        __syncthreads();
        float dot[4][4] = {};
        for (int d = 0; d < 128; ++d) {
            float a[4], b[4];
#pragma unroll
            for (int i = 0; i < 4; ++i) a[i] = iqs[ty + 16 * i][d];
#pragma unroll
            for (int j = 0; j < 4; ++j) b[j] = iks[tx + 16 * j][d];
#pragma unroll
            for (int i = 0; i < 4; ++i)
#pragma unroll
                for (int j = 0; j < 4; ++j)
                    dot[i][j] += a[i] * b[j];
        }
#pragma unroll
        for (int i = 0; i < 4; ++i)
#pragma unroll
            for (int j = 0; j < 4; ++j)
                acc[i][j] += iws[ty + 16 * i][h] * fmaxf(dot[i][j], 0.f);
    }
#pragma unroll
    for (int i = 0; i < 4; ++i) {
        int q = q0 + ty + 16 * i;
#pragma unroll
        for (int j = 0; j < 4; ++j) {
            int k = k0 + tx + 16 * j;
            scores[(size_t)q * SEQ + k] = (k <= q) ? acc[i][j] : -INFINITY;
        }
    }
}

// ---------------- top-512 per row via bitonic sort ----------------
__global__ __launch_bounds__(1024) void topk_kernel(
    const float* __restrict__ scores, int* __restrict__ sel)
{
    int qi = blockIdx.x, tid = threadIdx.x;
    __shared__ unsigned long long keys[2048];
    const float* srow = scores + (size_t)qi * SEQ;
#pragma unroll
    for (int r = 0; r < 2; ++r) {
        int k = tid + r * 1024;
        unsigned u = __float_as_uint(srow[k]);
        unsigned mv = (u & 0x80000000u) ? ~u : (u | 0x80000000u);
        keys[k] = ((unsigned long long)mv << 32) | (unsigned)(2047 - k);
    }
    for (int ksz = 2; ksz <= 2048; ksz <<= 1) {
        for (int j = ksz >> 1; j > 0; j >>= 1) {
            __syncthreads();
#pragma unroll 1
            for (int r = 0; r < 2; ++r) {
                int i = tid + r * 1024;
                int ixj = i ^ j;
                if (ixj > i) {
                    unsigned long long a = keys[i], b = keys[ixj];
                    bool dir = ((i & ksz) == 0);
                    if ((a < b) == dir) { keys[i] = b; keys[ixj] = a; }
                }
            }
        }
    }
    __syncthreads();
    if (tid < TOPK) {
        int k = 2047 - (int)(keys[tid] & 0xFFFFFFFFu);
        sel[(size_t)qi * TOPK + tid] = (tid <= qi) ? k : -1;
    }
}

// ---------------- MFMA flash-style absorbed sparse attention ----------------
// One block per q, 4 waves. Scores: waves split 64-key tile by 16 keys.
// PV: waves split the 512 compressed dims by 128. Online softmax shared via LDS.
__global__ __launch_bounds__(256) void attn_mfma_kernel(
    const unsigned short* __restrict__ qabs,  // (S,16,512) bf16
    const float* __restrict__ qsrc,           // qbuf (S,16,192) f32, qpe at +128
    const unsigned short* __restrict__ khg,   // (S,576) bf16: [ckvn|kpe]
    const int* __restrict__ sel,              // (S,512)
    unsigned short* __restrict__ ocomp)       // (S,16,512) bf16 normalized
{
    __shared__ __align__(16) unsigned short kh[64 * 576];  // swizzled rows of 1152B
    __shared__ __align__(16) unsigned short plds[64 * 16]; // P[key][head] bf16
    __shared__ float smax[4][16];
    __shared__ float ssum[4][16];
    __shared__ int selb[64];

    const int qi = blockIdx.x;
    const int tid = threadIdx.x;
    const int l = tid & 63, w = tid >> 6;
    const int lg = l >> 4, lr = l & 15;
    const int nv = min(TOPK, qi + 1);
    const int ntile = (nv + 63) >> 6;

    // A-fragments: qh[head=lr][k = lg*8 + ks*32 .. +8]
    short8v aq[18];
    {
        const unsigned short* qa = qabs + ((size_t)qi * 16 + lr) * 512 + lg * 8;
#pragma unroll
        for (int ks = 0; ks < 16; ++ks)
            aq[ks] = *(const short8v*)(qa + ks * 32);
        const float* qp = qsrc + (size_t)qi * 3072 + lr * 192 + 128 + lg * 8;
#pragma unroll
        for (int ks = 0; ks < 2; ++ks) {
            float4 f0 = *(const float4*)(qp + ks * 32);
            float4 f1 = *(const float4*)(qp + ks * 32 + 4);
            short8v d;
            d[0] = (short)f2bf(f0.x); d[1] = (short)f2bf(f0.y);
            d[2] = (short)f2bf(f0.z); d[3] = (short)f2bf(f0.w);
            d[4] = (short)f2bf(f1.x); d[5] = (short)f2bf(f1.y);
            d[6] = (short)f2bf(f1.z); d[7] = (short)f2bf(f1.w);
            aq[16 + ks] = d;
        }
    }

    float m[4] = {-1e30f, -1e30f, -1e30f, -1e30f};
    float lsum[4] = {0.f, 0.f, 0.f, 0.f};
    f32x4 oacc[8] = {};

    for (int t = 0; t < ntile; ++t) {
        const int j0 = t * 64;
        __syncthreads();
        if (tid < 64) {
            int sv = sel[(size_t)qi * TOPK + j0 + tid];
            selb[tid] = sv < 0 ? 0 : sv;
        }
        __syncthreads();
        // stage 64 keys: ckvn part (512) + kpe part (64), XOR-swizzled
        for (int it = tid; it < 64 * 64; it += 256) {
            int row = it >> 6, c = it & 63;
            short8v v = *(const short8v*)(khg + (size_t)selb[row] * 576 + c * 8);
            int addr = (row * 1152 + c * 16) ^ ((row & 7) << 4);
            *(short8v*)((char*)kh + addr) = v;
        }
        for (int it = tid; it < 64 * 8; it += 256) {
            int row = it >> 3, c = it & 7;
            short8v v = *(const short8v*)(khg + (size_t)selb[row] * 576 + 512 + c * 8);
            int addr = (row * 1152 + 1024 + c * 16) ^ ((row & 7) << 4);
            *(short8v*)((char*)kh + addr) = v;
        }
        __syncthreads();
        // scores for wave's 16 keys (key = j0 + w*16 + lr)
        f32x4 s = {};
        const int krow = w * 16 + lr;
#pragma unroll
        for (int ks = 0; ks < 18; ++ks) {
            int addr = (krow * 1152 + ks * 64 + lg * 16) ^ ((krow & 7) << 4);
            short8v b = *(const short8v*)((char*)kh + addr);
            s = __builtin_amdgcn_mfma_f32_16x16x32_bf16(aq[ks], b, s, 0, 0, 0);
        }
        bool kvalid = (j0 + krow) < nv;
#pragma unroll
        for (int i = 0; i < 4; ++i)
            s[i] = kvalid ? s[i] * SCALE_ATTN : -1e30f;
        // per-wave row max across the 16 key-lanes
        float tm[4];
#pragma unroll
        for (int i = 0; i < 4; ++i) tm[i] = s[i];
#pragma unroll
        for (int sh = 1; sh < 16; sh <<= 1)
#pragma unroll
            for (int i = 0; i < 4; ++i) tm[i] = fmaxf(tm[i], __shfl_xor(tm[i], sh));
        if (lr == 0) *(float4*)&smax[w][lg * 4] = make_float4(tm[0], tm[1], tm[2], tm[3]);
        __syncthreads();
        float mn[4], scl[4];
#pragma unroll
        for (int i = 0; i < 4; ++i) {
            int h = lg * 4 + i;
            float tmax = fmaxf(fmaxf(smax[0][h], smax[1][h]), fmaxf(smax[2][h], smax[3][h]));
            mn[i] = fmaxf(m[i], tmax);
            scl[i] = __expf(m[i] - mn[i]);
            m[i] = mn[i];
        }
        float p[4], rs[4];
#pragma unroll
        for (int i = 0; i < 4; ++i) { p[i] = __expf(s[i] - mn[i]); rs[i] = p[i]; }
#pragma unroll
        for (int sh = 1; sh < 16; sh <<= 1)
#pragma unroll
            for (int i = 0; i < 4; ++i) rs[i] += __shfl_xor(rs[i], sh);
        if (lr == 0) *(float4*)&ssum[w][lg * 4] = make_float4(rs[0], rs[1], rs[2], rs[3]);
        {
            ushort4 pb;
            pb.x = f2bf(p[0]); pb.y = f2bf(p[1]); pb.z = f2bf(p[2]); pb.w = f2bf(p[3]);
            *(ushort4*)&plds[(w * 16 + lr) * 16 + lg * 4] = pb;
        }
        __syncthreads();
#pragma unroll
        for (int i = 0; i < 4; ++i) {
            int h = lg * 4 + i;
            float ts = ssum[0][h] + ssum[1][h] + ssum[2][h] + ssum[3][h];
            lsum[i] = lsum[i] * scl[i] + ts;
        }
#pragma unroll
        for (int nt = 0; nt < 8; ++nt)
#pragma unroll
            for (int i = 0; i < 4; ++i) oacc[nt][i] *= scl[i];
        // PV: wave handles dims [w*128, w*128+128); K = 64 keys in 2 steps
#pragma unroll
        for (int kb = 0; kb < 2; ++kb) {
            short8v af;
#pragma unroll
            for (int j = 0; j < 8; ++j)
                af[j] = (short)plds[(kb * 32 + lg * 8 + j) * 16 + lr];
#pragma unroll
            for (int nt = 0; nt < 8; ++nt) {
                int d = w * 128 + nt * 16 + lr;
                short8v bf;
#pragma unroll
                for (int j = 0; j < 8; ++j) {
                    int key = kb * 32 + lg * 8 + j;
                    int addr = (key * 1152 + d * 2) ^ ((key & 7) << 4);
                    bf[j] = *(const short*)((char*)kh + addr);
                }
                oacc[nt] = __builtin_amdgcn_mfma_f32_16x16x32_bf16(af, bf, oacc[nt], 0, 0, 0);
            }
        }
    }
    float inv[4];
#pragma unroll
    for (int i = 0; i < 4; ++i) inv[i] = 1.f / lsum[i];
    unsigned short* ob = ocomp + (size_t)qi * 16 * 512;
#pragma unroll
    for (int nt = 0; nt < 8; ++nt) {
        int d = w * 128 + nt * 16 + lr;
#pragma unroll
        for (int i = 0; i < 4; ++i) {
            int h = lg * 4 + i;
            ob[h * 512 + d] = f2bf(oacc[nt][i] * inv[i]);
        }
    }
}

// ---------------- launcher ----------------
extern "C" void kernel_launch(void* const* d_in, const int* in_sizes, int n_in,
                              void* d_out, int out_size, void* d_ws, size_t ws_size,
                              hipStream_t stream) {
    (void)in_sizes; (void)n_in; (void)out_size; (void)ws_size;
    const float* hidden      = (const float*)d_in[0];
    const float* q_a_w       = (const float*)d_in[1];
    const float* q_a_ln_w    = (const float*)d_in[2];
    const float* q_b_w       = (const float*)d_in[3];
    const float* kv_a_w      = (const float*)d_in[4];
    const float* kv_a_ln_w   = (const float*)d_in[5];
    const float* kv_b_w      = (const float*)d_in[6];
    const float* o_w         = (const float*)d_in[7];
    const float* idx_wq_b_w  = (const float*)d_in[8];
    const float* idx_wk_w    = (const float*)d_in[9];
    const float* idx_kn_w    = (const float*)d_in[10];
    const float* idx_kn_b    = (const float*)d_in[11];
    const float* idx_wproj_w = (const float*)d_in[12];
    float* out = (float*)d_out;

    char* ws = (char*)d_ws;
    size_t off = 0;
    auto alloc = [&](size_t nbytes) -> void* {
        void* p = ws + off;
        off = (off + nbytes + 255) & ~(size_t)255;
        return p;
    };
    // persistent
    float* cos_t = (float*)alloc((size_t)SEQ * 32 * 4);
    float* sin_t = (float*)alloc((size_t)SEQ * 32 * 4);
    float* qbuf  = (float*)alloc((size_t)SEQ * 3072 * 4);
    float* ckv   = (float*)alloc((size_t)SEQ * 576 * 4);
    float* ckvn  = (float*)alloc((size_t)SEQ * KVRANK * 4);
    int*   sel   = (int*)alloc((size_t)SEQ * TOPK * 4);
    unsigned short* khg      = (unsigned short*)alloc((size_t)SEQ * 576 * 2);
    unsigned short* attno_bf = (unsigned short*)alloc((size_t)SEQ * 2048 * 2);
    unsigned short* qr_bf    = (unsigned short*)alloc((size_t)SEQ * QRANK * 2);
    unsigned short* q_b_bf   = (unsigned short*)alloc((size_t)3072 * QRANK * 2);
    unsigned short* kv_a_bf  = (unsigned short*)alloc((size_t)576 * HIDD * 2);
    unsigned short* o_w_bf   = (unsigned short*)alloc((size_t)HIDD * 2048 * 2);
    unsigned short* kv_b_bf  = (unsigned short*)alloc((size_t)4096 * 512 * 2);
    unsigned short* wkt      = (unsigned short*)alloc((size_t)16 * 512 * 128 * 2);
    size_t mark = off;
    // transients (dead after topk)
    float* qr    = (float*)alloc((size_t)SEQ * QRANK * 4);
    float* iqb   = (float*)alloc((size_t)SEQ * 2048 * 4);
    float* ikb   = (float*)alloc((size_t)SEQ * 128 * 4);
    float* iwb   = (float*)alloc((size_t)SEQ * 16 * 4);
    float* scores = (float*)alloc((size_t)SEQ * SEQ * 4);
    // overlay region (alive after topk)
    off = mark;
    unsigned short* qabsb = (unsigned short*)alloc((size_t)SEQ * 16 * 512 * 2);
    unsigned short* ocomp = (unsigned short*)alloc((size_t)SEQ * 16 * 512 * 2);

    rope_table_kernel<<<dim3(SEQ), dim3(32), 0, stream>>>(cos_t, sin_t);

    // weight converts
    cvt_bf16_kernel<<<1024, 256, 0, stream>>>(q_b_w, q_b_bf, 3072 * QRANK / 4);
    cvt_bf16_kernel<<<1024, 256, 0, stream>>>(kv_a_w, kv_a_bf, 576 * HIDD / 4);
    cvt_bf16_kernel<<<1024, 256, 0, stream>>>(o_w, o_w_bf, HIDD * 2048 / 4);
    cvt_bf16_kernel<<<1024, 256, 0, stream>>>(kv_b_w, kv_b_bf, 4096 * 512 / 4);
    wkt_kernel<<<4096, 256, 0, stream>>>(kv_b_w, wkt);

    // qr = rmsnorm(hidden @ q_a_w^T)  (exact f32 path; dual f32+bf16 out)
    gemm_nt_kernel<<<dim3(16, 12), 256, 0, stream>>>(hidden, q_a_w, qr, SEQ, QRANK, HIDD, HIDD, HIDD, QRANK, 1.f);
    rmsnorm_kernel<<<SEQ, 256, 0, stream>>>(qr, q_a_ln_w, qr, qr_bf, QRANK, QRANK);

    // q = qr @ q_b_w^T  (bf16 MFMA) ; rope on [128:192] per head
    mfma_nt_kernel<unsigned short, float><<<dim3(16, 24, 1), 256, 0, stream>>>(
        qr_bf, q_b_bf, qbuf, SEQ, 3072, QRANK, QRANK, QRANK, 3072, 0L, 0L, 0L);
    rope_apply_kernel<<<(SEQ * 16 * 32) / 256, 256, 0, stream>>>(qbuf, cos_t, sin_t, 16, 3072, 192, 128);

    // ckv = hidden @ kv_a_w^T (MFMA); rope kpe; rmsnorm -> ckvn; build bf16 khg
    mfma_nt_kernel<float, float><<<dim3(16, 5, 1), 256, 0, stream>>>(
        hidden, kv_a_bf, ckv, SEQ, 576, HIDD, HIDD, HIDD, 576, 0L, 0L, 0L);
    rope_apply_kernel<<<(SEQ * 32) / 256, 256, 0, stream>>>(ckv, cos_t, sin_t, 1, 576, 0, 512);
    rmsnorm_kernel<<<SEQ, 256, 0, stream>>>(ckv, kv_a_ln_w, ckvn, nullptr, KVRANK, 576);
    khg_kernel<<<SEQ, 256, 0, stream>>>(ckvn, ckv, khg);

    // indexer path: exact f32
    gemm_nt_kernel<<<dim3(16, 16), 256, 0, stream>>>(qr, idx_wq_b_w, iqb, SEQ, 2048, QRANK, QRANK, QRANK, 2048, 1.f);
    rope_apply_kernel<<<(SEQ * 16 * 32) / 256, 256, 0, stream>>>(iqb, cos_t, sin_t, 16, 2048, 128, 0);
    gemm_nt_kernel<<<dim3(16, 1), 256, 0, stream>>>(hidden, idx_wk_w, ikb, SEQ, IDIM, HIDD, HIDD, HIDD, IDIM, 1.f);
    layernorm_kernel<<<SEQ, 64, 0, stream>>>(ikb, idx_kn_w, idx_kn_b, ikb);
    rope_apply_kernel<<<(SEQ * 32) / 256, 256, 0, stream>>>(ikb, cos_t, sin_t, 1, 128, 0, 0);
    gemm_nt_kernel<<<dim3(16, 1), 256, 0, stream>>>(hidden, idx_wproj_w, iwb, SEQ, IHEAD, HIDD, HIDD, HIDD, IHEAD, 0.25f);
    idx_scores_kernel<<<dim3(32, 32), 256, 0, stream>>>(iqb, ikb, iwb, scores);
    topk_kernel<<<SEQ, 1024, 0, stream>>>(scores, sel);

    // q absorption (bf16 MFMA, batched per head)
    mfma_nt_kernel<float, unsigned short><<<dim3(16, 4, 16), 256, 0, stream>>>(
        qbuf, wkt, qabsb, SEQ, 512, 128, 3072, 128, 16 * 512,
        192L, 512L * 128L, 512L);

    // MFMA flash attention over selected keys -> ocomp (normalized bf16)
    attn_mfma_kernel<<<SEQ, 256, 0, stream>>>(qabsb, qbuf, khg, sel, ocomp);

    // output projection (bf16 MFMA, batched)
    mfma_nt_kernel<unsigned short, unsigned short><<<dim3(16, 1, 16), 256, 0, stream>>>(
        ocomp, kv_b_bf + (size_t)128 * 512, attno_bf, SEQ, 128, 512,
        16 * 512, 512, 2048, 512L, 256L * 512L, 128L);

    // out = attno @ o_w^T (bf16 MFMA)
    mfma_nt_kernel<unsigned short, float><<<dim3(16, 16, 1), 256, 0, stream>>>(
        attno_bf, o_w_bf, out, SEQ, HIDD, 2048, 2048, 2048, HIDD, 0L, 0L, 0L);
}

// Round 5
// 1089.916 us; speedup vs baseline: 4.4023x; 2.3004x over previous
//
#include <hip/hip_runtime.h>
#include <hip/hip_bf16.h>
#include <math.h>

#define SEQ 2048
#define HIDD 2048
#define QRANK 1536
#define KVRANK 512
#define TOPK 512
#define EPSF 1e-6f
#define SCALE_ATTN 0.07216878364870323f  /* 192^-0.5 */
#define NCAT 1680

typedef __attribute__((ext_vector_type(8))) short short8v;
typedef __attribute__((ext_vector_type(4))) float f32x4;

__device__ inline unsigned short f2bf(float f) {
    unsigned u = __float_as_uint(f);
    unsigned r = (u + 0x7FFFu + ((u >> 16) & 1u)) >> 16;
    return (unsigned short)r;
}
__device__ inline float bf2f(unsigned short b) {
    return __uint_as_float(((unsigned)b) << 16);
}
__device__ inline void split2(float x, unsigned short& h, unsigned short& l) {
    h = f2bf(x);
    l = f2bf(x - bf2f(h));
}

// ---------------- RoPE cos/sin table ----------------
__global__ void rope_table_kernel(float* __restrict__ cos_t, float* __restrict__ sin_t) {
    int s = blockIdx.x;
    int i = threadIdx.x;  // 0..31
    double inv = pow(10000.0, -((double)(2 * i)) / 64.0);
    double f = (double)s * inv;
    cos_t[s * 32 + i] = (float)cos(f);
    sin_t[s * 32 + i] = (float)sin(f);
}

// ---------------- f32 -> bf16 convert ----------------
__global__ __launch_bounds__(256) void cvt_bf16_kernel(const float* __restrict__ in,
                                                       unsigned short* __restrict__ out, int n4) {
    for (int i = blockIdx.x * 256 + threadIdx.x; i < n4; i += gridDim.x * 256) {
        float4 v = ((const float4*)in)[i];
        ushort4 o;
        o.x = f2bf(v.x); o.y = f2bf(v.y); o.z = f2bf(v.z); o.w = f2bf(v.w);
        ((ushort4*)out)[i] = o;
    }
}

// ---------------- transpose k-absorb weights: wkt[h][n][d] = kv_b_w[h*256+d][n] ----------------
__global__ __launch_bounds__(256) void wkt_kernel(const float* __restrict__ kvb,
                                                  unsigned short* __restrict__ wkt) {
    int o = blockIdx.x * 256 + threadIdx.x;
    int d = o & 127;
    int n = (o >> 7) & 511;
    int h = o >> 16;
    wkt[o] = f2bf(kvb[((size_t)(h * 256 + d)) * 512 + n]);
}

// ---------------- kh_g[s][0:512]=bf16(ckvn[s]); [512:576]=bf16(roped kpe) ----------------
__global__ __launch_bounds__(256) void khg_kernel(const float* __restrict__ ckvn,
                                                  const float* __restrict__ ckv,
                                                  unsigned short* __restrict__ khg) {
    int s = blockIdx.x;
    for (int i = threadIdx.x; i < 576; i += 256) {
        float v = (i < 512) ? ckvn[(size_t)s * 512 + i] : ckv[(size_t)s * 576 + i];
        khg[(size_t)s * 576 + i] = f2bf(v);
    }
}

// ---------------- split-bf16 3-pass MFMA cat-GEMM: ccat = hidden @ [q_a_w; idx_wk_w; .25*wproj]^T ----------------
__global__ __launch_bounds__(256) void gemm_cat_split_kernel(
    const float* __restrict__ hidden, const float* __restrict__ q_a_w,
    const float* __restrict__ idx_wk_w, const float* __restrict__ idx_wproj_w,
    float* __restrict__ ccat)
{
    __shared__ __align__(16) unsigned short Ah[128 * 32], Al[128 * 32];
    __shared__ __align__(16) unsigned short Bh[128 * 32], Bl[128 * 32];
    int tid = threadIdx.x;
    int l = tid & 63, w = tid >> 6;
    int wr = w >> 1, wc = w & 1;
    int m0 = blockIdx.x * 128, n0 = blockIdx.y * 128;
    f32x4 acc[4][4] = {};
    for (int k0 = 0; k0 < HIDD; k0 += 32) {
        __syncthreads();
#pragma unroll
        for (int i = 0; i < 2; ++i) {
            int idx = tid + i * 256;
            int r = idx >> 2, cc = idx & 3;
            int sw = cc ^ (r & 3);
            {
                const float* src = hidden + (size_t)(m0 + r) * HIDD + k0 + cc * 8;
                float4 f0 = *(const float4*)src, f1 = *(const float4*)(src + 4);
                float xs[8] = {f0.x, f0.y, f0.z, f0.w, f1.x, f1.y, f1.z, f1.w};
                short8v dh, dl;
#pragma unroll
                for (int e = 0; e < 8; ++e) {
                    unsigned short hh, ll; split2(xs[e], hh, ll);
                    dh[e] = (short)hh; dl[e] = (short)ll;
                }
                *(short8v*)&Ah[r * 32 + sw * 8] = dh;
                *(short8v*)&Al[r * 32 + sw * 8] = dl;
            }
            {
                int gb = n0 + r; if (gb > NCAT - 1) gb = NCAT - 1;
                float scale = 1.f;
                const float* src;
                if (gb < 1536) src = q_a_w + (size_t)gb * HIDD;
                else if (gb < 1664) src = idx_wk_w + (size_t)(gb - 1536) * HIDD;
                else { src = idx_wproj_w + (size_t)(gb - 1664) * HIDD; scale = 0.25f; }
                src += k0 + cc * 8;
                float4 f0 = *(const float4*)src, f1 = *(const float4*)(src + 4);
                float xs[8] = {f0.x, f0.y, f0.z, f0.w, f1.x, f1.y, f1.z, f1.w};
                short8v dh, dl;
#pragma unroll
                for (int e = 0; e < 8; ++e) {
                    unsigned short hh, ll; split2(xs[e] * scale, hh, ll);
                    dh[e] = (short)hh; dl[e] = (short)ll;
                }
                *(short8v*)&Bh[r * 32 + sw * 8] = dh;
                *(short8v*)&Bl[r * 32 + sw * 8] = dl;
            }
        }
        __syncthreads();
        short8v avh[4], avl[4];
#pragma unroll
        for (int mt = 0; mt < 4; ++mt) {
            int row = wr * 64 + mt * 16 + (l & 15);
            int ch = (l >> 4) ^ (row & 3);
            avh[mt] = *(const short8v*)&Ah[row * 32 + ch * 8];
            avl[mt] = *(const short8v*)&Al[row * 32 + ch * 8];
        }
#pragma unroll
        for (int nt = 0; nt < 4; ++nt) {
            int row = wc * 64 + nt * 16 + (l & 15);
            int ch = (l >> 4) ^ (row & 3);
            short8v bvh = *(const short8v*)&Bh[row * 32 + ch * 8];
            short8v bvl = *(const short8v*)&Bl[row * 32 + ch * 8];
#pragma unroll
            for (int mt = 0; mt < 4; ++mt) {
                acc[mt][nt] = __builtin_amdgcn_mfma_f32_16x16x32_bf16(avh[mt], bvh, acc[mt][nt], 0, 0, 0);
                acc[mt][nt] = __builtin_amdgcn_mfma_f32_16x16x32_bf16(avh[mt], bvl, acc[mt][nt], 0, 0, 0);
                acc[mt][nt] = __builtin_amdgcn_mfma_f32_16x16x32_bf16(avl[mt], bvh, acc[mt][nt], 0, 0, 0);
            }
        }
    }
#pragma unroll
    for (int mt = 0; mt < 4; ++mt)
#pragma unroll
        for (int nt = 0; nt < 4; ++nt)
#pragma unroll
            for (int i = 0; i < 4; ++i) {
                int gm = m0 + wr * 64 + mt * 16 + (l >> 4) * 4 + i;
                int gn = n0 + wc * 64 + nt * 16 + (l & 15);
                if (gn < NCAT) ccat[(size_t)gm * NCAT + gn] = acc[mt][nt][i];
            }
}

// ---------------- split-bf16 3-pass MFMA iq-GEMM with fused RoPE + hi/lo split output ----------------
// iq = qr @ idx_wq_b_w^T; each 128-col tile == one indexer head; rope dims [0:64).
__global__ __launch_bounds__(256) void gemm_iq_split_kernel(
    const float* __restrict__ qr, const float* __restrict__ wq,
    const float* __restrict__ cos_t, const float* __restrict__ sin_t,
    unsigned short* __restrict__ iqh, unsigned short* __restrict__ iql)
{
    __shared__ __align__(16) unsigned short Ah[128 * 32], Al[128 * 32];
    __shared__ __align__(16) unsigned short Bh[128 * 32], Bl[128 * 32];
    int tid = threadIdx.x;
    int l = tid & 63, w = tid >> 6;
    int wr = w >> 1, wc = w & 1;
    int m0 = blockIdx.x * 128, n0 = blockIdx.y * 128;
    int hh_ = blockIdx.y;  // head
    f32x4 acc[4][4] = {};
    for (int k0 = 0; k0 < QRANK; k0 += 32) {
        __syncthreads();
#pragma unroll
        for (int i = 0; i < 2; ++i) {
            int idx = tid + i * 256;
            int r = idx >> 2, cc = idx & 3;
            int sw = cc ^ (r & 3);
            {
                const float* src = qr + (size_t)(m0 + r) * QRANK + k0 + cc * 8;
                float4 f0 = *(const float4*)src, f1 = *(const float4*)(src + 4);
                float xs[8] = {f0.x, f0.y, f0.z, f0.w, f1.x, f1.y, f1.z, f1.w};
                short8v dh, dl;
#pragma unroll
                for (int e = 0; e < 8; ++e) {
                    unsigned short h2, l2; split2(xs[e], h2, l2);
                    dh[e] = (short)h2; dl[e] = (short)l2;
                }
                *(short8v*)&Ah[r * 32 + sw * 8] = dh;
                *(short8v*)&Al[r * 32 + sw * 8] = dl;
            }
            {
                const float* src = wq + (size_t)(n0 + r) * QRANK + k0 + cc * 8;
                float4 f0 = *(const float4*)src, f1 = *(const float4*)(src + 4);
                float xs[8] = {f0.x, f0.y, f0.z, f0.w, f1.x, f1.y, f1.z, f1.w};
                short8v dh, dl;
#pragma unroll
                for (int e = 0; e < 8; ++e) {
                    unsigned short h2, l2; split2(xs[e], h2, l2);
                    dh[e] = (short)h2; dl[e] = (short)l2;
                }
                *(short8v*)&Bh[r * 32 + sw * 8] = dh;
                *(short8v*)&Bl[r * 32 + sw * 8] = dl;
            }
        }
        __syncthreads();
        short8v avh[4], avl[4];
#pragma unroll
        for (int mt = 0; mt < 4; ++mt) {
            int row = wr * 64 + mt * 16 + (l & 15);
            int ch = (l >> 4) ^ (row & 3);
            avh[mt] = *(const short8v*)&Ah[row * 32 + ch * 8];
            avl[mt] = *(const short8v*)&Al[row * 32 + ch * 8];
        }
#pragma unroll
        for (int nt = 0; nt < 4; ++nt) {
            int row = wc * 64 + nt * 16 + (l & 15);
            int ch = (l >> 4) ^ (row & 3);
            short8v bvh = *(const short8v*)&Bh[row * 32 + ch * 8];
            short8v bvl = *(const short8v*)&Bl[row * 32 + ch * 8];
#pragma unroll
            for (int mt = 0; mt < 4; ++mt) {
                acc[mt][nt] = __builtin_amdgcn_mfma_f32_16x16x32_bf16(avh[mt], bvh, acc[mt][nt], 0, 0, 0);
                acc[mt][nt] = __builtin_amdgcn_mfma_f32_16x16x32_bf16(avh[mt], bvl, acc[mt][nt], 0, 0, 0);
                acc[mt][nt] = __builtin_amdgcn_mfma_f32_16x16x32_bf16(avl[mt], bvh, acc[mt][nt], 0, 0, 0);
            }
        }
    }
    // fused RoPE on cols [0,64): pair (d, d+32) = (nt, nt+2), only wc==0 waves
    if (wc == 0) {
#pragma unroll
        for (int mt = 0; mt < 4; ++mt)
#pragma unroll
            for (int nt = 0; nt < 2; ++nt)
#pragma unroll
                for (int i = 0; i < 4; ++i) {
                    int q = m0 + wr * 64 + mt * 16 + (l >> 4) * 4 + i;
                    int dd = nt * 16 + (l & 15);
                    float c = cos_t[q * 32 + dd], s = sin_t[q * 32 + dd];
                    float x1 = acc[mt][nt][i], x2 = acc[mt][nt + 2][i];
                    acc[mt][nt][i] = x1 * c - x2 * s;
                    acc[mt][nt + 2][i] = x2 * c + x1 * s;
                }
    }
#pragma unroll
    for (int mt = 0; mt < 4; ++mt)
#pragma unroll
        for (int nt = 0; nt < 4; ++nt)
#pragma unroll
            for (int i = 0; i < 4; ++i) {
                int q = m0 + wr * 64 + mt * 16 + (l >> 4) * 4 + i;
                int d = wc * 64 + nt * 16 + (l & 15);
                size_t idx = ((size_t)q * 16 + hh_) * 128 + d;
                unsigned short h2, l2; split2(acc[mt][nt][i], h2, l2);
                iqh[idx] = h2; iql[idx] = l2;
            }
}

// ---------------- bf16 MFMA NT GEMM, batched (main path) ----------------
template <typename TA, typename TC>
__global__ __launch_bounds__(256) void mfma_nt_kernel(
    const TA* __restrict__ A, const unsigned short* __restrict__ B, TC* __restrict__ C,
    int M, int N, int K, int lda, int ldb, int ldc, long ab, long bb, long cb)
{
    __shared__ __align__(16) unsigned short Asl[128 * 32];
    __shared__ __align__(16) unsigned short Bsl[128 * 32];
    int z = blockIdx.z;
    const TA* Az = A + (size_t)z * ab;
    const unsigned short* Bz = B + (size_t)z * bb;
    TC* Cz = C + (size_t)z * cb;
    int tid = threadIdx.x;
    int l = tid & 63, w = tid >> 6;
    int wr = w >> 1, wc = w & 1;
    int m0 = blockIdx.x * 128, n0 = blockIdx.y * 128;
    f32x4 acc[4][4] = {};

    for (int k0 = 0; k0 < K; k0 += 32) {
        __syncthreads();
#pragma unroll
        for (int i = 0; i < 2; ++i) {
            int idx = tid + i * 256;
            int r = idx >> 2, cc = idx & 3;
            int sw = cc ^ (r & 3);
            {
                short8v d;
                const TA* src = Az + (size_t)(m0 + r) * lda + k0 + cc * 8;
                if constexpr (sizeof(TA) == 2) {
                    d = *(const short8v*)src;
                } else {
                    float4 f0 = *(const float4*)src;
                    float4 f1 = *(const float4*)(src + 4);
                    d[0] = (short)f2bf(f0.x); d[1] = (short)f2bf(f0.y);
                    d[2] = (short)f2bf(f0.z); d[3] = (short)f2bf(f0.w);
                    d[4] = (short)f2bf(f1.x); d[5] = (short)f2bf(f1.y);
                    d[6] = (short)f2bf(f1.z); d[7] = (short)f2bf(f1.w);
                }
                *(short8v*)&Asl[r * 32 + sw * 8] = d;
            }
            {
                int gb = n0 + r; if (gb > N - 1) gb = N - 1;
                short8v d = *(const short8v*)(Bz + (size_t)gb * ldb + k0 + cc * 8);
                *(short8v*)&Bsl[r * 32 + sw * 8] = d;
            }
        }
        __syncthreads();
        short8v av[4], bv[4];
#pragma unroll
        for (int mt = 0; mt < 4; ++mt) {
            int row = wr * 64 + mt * 16 + (l & 15);
            int ch = (l >> 4) ^ (row & 3);
            av[mt] = *(const short8v*)&Asl[row * 32 + ch * 8];
        }
#pragma unroll
        for (int nt = 0; nt < 4; ++nt) {
            int row = wc * 64 + nt * 16 + (l & 15);
            int ch = (l >> 4) ^ (row & 3);
            bv[nt] = *(const short8v*)&Bsl[row * 32 + ch * 8];
        }
#pragma unroll
        for (int mt = 0; mt < 4; ++mt)
#pragma unroll
            for (int nt = 0; nt < 4; ++nt)
                acc[mt][nt] = __builtin_amdgcn_mfma_f32_16x16x32_bf16(av[mt], bv[nt], acc[mt][nt], 0, 0, 0);
    }
#pragma unroll
    for (int mt = 0; mt < 4; ++mt) {
#pragma unroll
        for (int nt = 0; nt < 4; ++nt) {
#pragma unroll
            for (int i = 0; i < 4; ++i) {
                int gm = m0 + wr * 64 + mt * 16 + (l >> 4) * 4 + i;
                int gn = n0 + wc * 64 + nt * 16 + (l & 15);
                if (gn < N) {
                    float v = acc[mt][nt][i];
                    if constexpr (sizeof(TC) == 4) Cz[(size_t)gm * ldc + gn] = v;
                    else Cz[(size_t)gm * ldc + gn] = f2bf(v);
                }
            }
        }
    }
}

// ---------------- RMSNorm, optional bf16 secondary output ----------------
__global__ __launch_bounds__(256) void rmsnorm_kernel(
    const float* __restrict__ in, const float* __restrict__ w, float* __restrict__ out,
    unsigned short* __restrict__ bf_out, int n, int in_stride)
{
    int row = blockIdx.x, tid = threadIdx.x;
    const float* x = in + (size_t)row * in_stride;
    float4 v[2];
    int cnt = 0;
    float ss = 0.f;
    int nf4 = n >> 2;
    for (int i = tid; i < nf4; i += 256) {
        float4 t = *(const float4*)(x + i * 4);
        v[cnt++] = t;
        ss += t.x * t.x + t.y * t.y + t.z * t.z + t.w * t.w;
    }
#pragma unroll
    for (int m = 32; m; m >>= 1) ss += __shfl_xor(ss, m);
    __shared__ float red[8];
    int wid = tid >> 6;
    if ((tid & 63) == 0) red[wid] = ss;
    __syncthreads();
    if (tid == 0) {
        float s = red[0] + red[1] + red[2] + red[3];
        red[4] = rsqrtf(s / (float)n + EPSF);
    }
    __syncthreads();
    float scale = red[4];
    cnt = 0;
    for (int i = tid; i < nf4; i += 256) {
        float4 t = v[cnt++];
        float4 wv = *(const float4*)(w + i * 4);
        float4 o;
        o.x = t.x * scale * wv.x; o.y = t.y * scale * wv.y;
        o.z = t.z * scale * wv.z; o.w = t.w * scale * wv.w;
        *(float4*)(out + (size_t)row * n + i * 4) = o;
        if (bf_out) {
            ushort4 ob;
            ob.x = f2bf(o.x); ob.y = f2bf(o.y); ob.z = f2bf(o.z); ob.w = f2bf(o.w);
            *(ushort4*)(bf_out + (size_t)row * n + i * 4) = ob;
        }
    }
}

// ---------------- LayerNorm + RoPE + hi/lo split for ik (row length 128) ----------------
__global__ __launch_bounds__(64) void ln_rope_split_kernel(
    const float* __restrict__ in, int stride,
    const float* __restrict__ w, const float* __restrict__ b,
    const float* __restrict__ cos_t, const float* __restrict__ sin_t,
    unsigned short* __restrict__ ikh, unsigned short* __restrict__ ikl)
{
    int row = blockIdx.x, tid = threadIdx.x;
    const float* x = in + (size_t)row * stride;
    float x0 = x[tid], x1 = x[tid + 64];
    float s = x0 + x1, ss = x0 * x0 + x1 * x1;
#pragma unroll
    for (int m = 32; m; m >>= 1) { s += __shfl_xor(s, m); ss += __shfl_xor(ss, m); }
    float mean = s * (1.f / 128.f);
    float var = ss * (1.f / 128.f) - mean * mean;
    float r = rsqrtf(var + EPSF);
    float n0 = (x0 - mean) * r * w[tid] + b[tid];
    float n1 = (x1 - mean) * r * w[tid + 64] + b[tid + 64];
    float c = cos_t[row * 32 + (tid & 31)], sn = sin_t[row * 32 + (tid & 31)];
    float other = __shfl_xor(n0, 32);
    float r0 = (tid < 32) ? (n0 * c - other * sn) : (n0 * c + other * sn);
    unsigned short h2, l2;
    split2(r0, h2, l2);
    ikh[(size_t)row * 128 + tid] = h2; ikl[(size_t)row * 128 + tid] = l2;
    split2(n1, h2, l2);
    ikh[(size_t)row * 128 + 64 + tid] = h2; ikl[(size_t)row * 128 + 64 + tid] = l2;
}

// ---------------- RoPE in-place ----------------
__global__ void rope_apply_kernel(
    float* __restrict__ x, const float* __restrict__ cos_t, const float* __restrict__ sin_t,
    int heads, int row_stride, int head_stride, int offset)
{
    int t = blockIdx.x * blockDim.x + threadIdx.x;
    int i = t & 31;
    int hh = (t >> 5) % heads;
    int r = t / (32 * heads);
    if (r >= SEQ) return;
    float* p = x + (size_t)r * row_stride + hh * head_stride + offset;
    float c = cos_t[r * 32 + i], s = sin_t[r * 32 + i];
    float x1 = p[i], x2 = p[i + 32];
    p[i] = x1 * c - x2 * s;
    p[i + 32] = x2 * c + x1 * s;
}

// ---------------- indexer scores via split-bf16 3-pass MFMA ----------------
__global__ __launch_bounds__(256) void idx_scores_mfma_kernel(
    const unsigned short* __restrict__ iqh, const unsigned short* __restrict__ iql,  // (S,16,128)
    const unsigned short* __restrict__ ikh, const unsigned short* __restrict__ ikl,  // (S,128)
    const float* __restrict__ iwsrc, int iw_stride,                                  // ccat+1664
    float* __restrict__ scores)
{
    int q0 = blockIdx.x * 64, k0 = blockIdx.y * 64;
    int tid = threadIdx.x;
    if (k0 > q0 + 63) {
        for (int t = tid; t < 64 * 64; t += 256) {
            int r = t >> 6, c = t & 63;
            scores[(size_t)(q0 + r) * SEQ + k0 + c] = -INFINITY;
        }
        return;
    }
    __shared__ __align__(16) unsigned short skh[64 * 128], skl[64 * 128];
    __shared__ __align__(16) unsigned short sqh[64 * 128], sql[64 * 128];
    __shared__ float iws[64][16];
    int l = tid & 63, w = tid >> 6;
    // stage ik tiles (once)
    for (int it = tid; it < 64 * 16; it += 256) {
        int r = it >> 4, c = it & 15;
        int sw = c ^ (r & 15);
        *(short8v*)&skh[r * 128 + sw * 8] = *(const short8v*)(ikh + (size_t)(k0 + r) * 128 + c * 8);
        *(short8v*)&skl[r * 128 + sw * 8] = *(const short8v*)(ikl + (size_t)(k0 + r) * 128 + c * 8);
    }
    {
        int r = tid >> 2, c = tid & 3;
        *(float4*)&iws[r][c * 4] = *(const float4*)(iwsrc + (size_t)(q0 + r) * iw_stride + c * 4);
    }
    f32x4 acc[4] = {};
    for (int h = 0; h < 16; ++h) {
        __syncthreads();
        for (int it = tid; it < 64 * 16; it += 256) {
            int r = it >> 4, c = it & 15;
            int sw = c ^ (r & 15);
            size_t base = ((size_t)(q0 + r) * 16 + h) * 128 + c * 8;
            *(short8v*)&sqh[r * 128 + sw * 8] = *(const short8v*)(iqh + base);
            *(short8v*)&sql[r * 128 + sw * 8] = *(const short8v*)(iql + base);
        }
        __syncthreads();
        f32x4 dot[4] = {};
#pragma unroll
        for (int ks = 0; ks < 4; ++ks) {
            int arow = w * 16 + (l & 15);
            int ach = ((l >> 4) + ks * 4) ^ (arow & 15);
            short8v ah = *(const short8v*)&sqh[arow * 128 + ach * 8];
            short8v al = *(const short8v*)&sql[arow * 128 + ach * 8];
#pragma unroll
            for (int nt = 0; nt < 4; ++nt) {
                int brow = nt * 16 + (l & 15);
                int bch = ((l >> 4) + ks * 4) ^ (brow & 15);
                short8v bh = *(const short8v*)&skh[brow * 128 + bch * 8];
                short8v bl = *(const short8v*)&skl[brow * 128 + bch * 8];
                dot[nt] = __builtin_amdgcn_mfma_f32_16x16x32_bf16(ah, bh, dot[nt], 0, 0, 0);
                dot[nt] = __builtin_amdgcn_mfma_f32_16x16x32_bf16(ah, bl, dot[nt], 0, 0, 0);
                dot[nt] = __builtin_amdgcn_mfma_f32_16x16x32_bf16(al, bh, dot[nt], 0, 0, 0);
            }
        }
#pragma unroll
        for (int nt = 0; nt < 4; ++nt)
#pragma unroll
            for (int i = 0; i < 4; ++i) {
                float wv = iws[w * 16 + (l >> 4) * 4 + i][h];
                acc[nt][i] += wv * fmaxf(dot[nt][i], 0.f);
            }
    }
#pragma unroll
    for (int nt = 0; nt < 4; ++nt)
#pragma unroll
        for (int i = 0; i < 4; ++i) {
            int q = q0 + w * 16 + (l >> 4) * 4 + i;
            int k = k0 + nt * 16 + (l & 15);
            scores[(size_t)q * SEQ + k] = (k <= q) ? acc[nt][i] : -INFINITY;
        }
}

// ---------------- top-512 per row via bitonic sort ----------------
__global__ __launch_bounds__(1024) void topk_kernel(
    const float* __restrict__ scores, int* __restrict__ sel)
{
    int qi = blockIdx.x, tid = threadIdx.x;
    __shared__ unsigned long long keys[2048];
    const float* srow = scores + (size_t)qi * SEQ;
#pragma unroll
    for (int r = 0; r < 2; ++r) {
        int k = tid + r * 1024;
        unsigned u = __float_as_uint(srow[k]);
        unsigned mv = (u & 0x80000000u) ? ~u : (u | 0x80000000u);
        keys[k] = ((unsigned long long)mv << 32) | (unsigned)(2047 - k);
    }
    for (int ksz = 2; ksz <= 2048; ksz <<= 1) {
        for (int j = ksz >> 1; j > 0; j >>= 1) {
            __syncthreads();
#pragma unroll 1
            for (int r = 0; r < 2; ++r) {
                int i = tid + r * 1024;
                int ixj = i ^ j;
                if (ixj > i) {
                    unsigned long long a = keys[i], b = keys[ixj];
                    bool dir = ((i & ksz) == 0);
                    if ((a < b) == dir) { keys[i] = b; keys[ixj] = a; }
                }
            }
        }
    }
    __syncthreads();
    if (tid < TOPK) {
        int k = 2047 - (int)(keys[tid] & 0xFFFFFFFFu);
        sel[(size_t)qi * TOPK + tid] = (tid <= qi) ? k : -1;
    }
}

// ---------------- MFMA flash-style absorbed sparse attention ----------------
__global__ __launch_bounds__(256) void attn_mfma_kernel(
    const unsigned short* __restrict__ qabs,  // (S,16,512) bf16
    const float* __restrict__ qsrc,           // qbuf (S,16,192) f32, qpe at +128
    const unsigned short* __restrict__ khg,   // (S,576) bf16: [ckvn|kpe]
    const int* __restrict__ sel,              // (S,512)
    unsigned short* __restrict__ ocomp)       // (S,16,512) bf16 normalized
{
    __shared__ __align__(16) unsigned short kh[64 * 576];
    __shared__ __align__(16) unsigned short plds[64 * 16];
    __shared__ float smax[4][16];
    __shared__ float ssum[4][16];
    __shared__ int selb[64];

    const int qi = blockIdx.x;
    const int tid = threadIdx.x;
    const int l = tid & 63, w = tid >> 6;
    const int lg = l >> 4, lr = l & 15;
    const int nv = min(TOPK, qi + 1);
    const int ntile = (nv + 63) >> 6;

    short8v aq[18];
    {
        const unsigned short* qa = qabs + ((size_t)qi * 16 + lr) * 512 + lg * 8;
#pragma unroll
        for (int ks = 0; ks < 16; ++ks)
            aq[ks] = *(const short8v*)(qa + ks * 32);
        const float* qp = qsrc + (size_t)qi * 3072 + lr * 192 + 128 + lg * 8;
#pragma unroll
        for (int ks = 0; ks < 2; ++ks) {
            float4 f0 = *(const float4*)(qp + ks * 32);
            float4 f1 = *(const float4*)(qp + ks * 32 + 4);
            short8v d;
            d[0] = (short)f2bf(f0.x); d[1] = (short)f2bf(f0.y);
            d[2] = (short)f2bf(f0.z); d[3] = (short)f2bf(f0.w);
            d[4] = (short)f2bf(f1.x); d[5] = (short)f2bf(f1.y);
            d[6] = (short)f2bf(f1.z); d[7] = (short)f2bf(f1.w);
            aq[16 + ks] = d;
        }
    }

    float m[4] = {-1e30f, -1e30f, -1e30f, -1e30f};
    float lsum[4] = {0.f, 0.f, 0.f, 0.f};
    f32x4 oacc[8] = {};

    for (int t = 0; t < ntile; ++t) {
        const int j0 = t * 64;
        __syncthreads();
        if (tid < 64) {
            int sv = sel[(size_t)qi * TOPK + j0 + tid];
            selb[tid] = sv < 0 ? 0 : sv;
        }
        __syncthreads();
        for (int it = tid; it < 64 * 64; it += 256) {
            int row = it >> 6, c = it & 63;
            short8v v = *(const short8v*)(khg + (size_t)selb[row] * 576 + c * 8);
            int addr = (row * 1152 + c * 16) ^ ((row & 7) << 4);
            *(short8v*)((char*)kh + addr) = v;
        }
        for (int it = tid; it < 64 * 8; it += 256) {
            int row = it >> 3, c = it & 7;
            short8v v = *(const short8v*)(khg + (size_t)selb[row] * 576 + 512 + c * 8);
            int addr = (row * 1152 + 1024 + c * 16) ^ ((row & 7) << 4);
            *(short8v*)((char*)kh + addr) = v;
        }
        __syncthreads();
        f32x4 s = {};
        const int krow = w * 16 + lr;
#pragma unroll
        for (int ks = 0; ks < 18; ++ks) {
            int addr = (krow * 1152 + ks * 64 + lg * 16) ^ ((krow & 7) << 4);
            short8v b = *(const short8v*)((char*)kh + addr);
            s = __builtin_amdgcn_mfma_f32_16x16x32_bf16(aq[ks], b, s, 0, 0, 0);
        }
        bool kvalid = (j0 + krow) < nv;
#pragma unroll
        for (int i = 0; i < 4; ++i)
            s[i] = kvalid ? s[i] * SCALE_ATTN : -1e30f;
        float tm[4];
#pragma unroll
        for (int i = 0; i < 4; ++i) tm[i] = s[i];
#pragma unroll
        for (int sh = 1; sh < 16; sh <<= 1)
#pragma unroll
            for (int i = 0; i < 4; ++i) tm[i] = fmaxf(tm[i], __shfl_xor(tm[i], sh));
        if (lr == 0) *(float4*)&smax[w][lg * 4] = make_float4(tm[0], tm[1], tm[2], tm[3]);
        __syncthreads();
        float mn[4], scl[4];
#pragma unroll
        for (int i = 0; i < 4; ++i) {
            int h = lg * 4 + i;
            float tmax = fmaxf(fmaxf(smax[0][h], smax[1][h]), fmaxf(smax[2][h], smax[3][h]));
            mn[i] = fmaxf(m[i], tmax);
            scl[i] = __expf(m[i] - mn[i]);
            m[i] = mn[i];
        }
        float p[4], rs[4];
#pragma unroll
        for (int i = 0; i < 4; ++i) { p[i] = __expf(s[i] - mn[i]); rs[i] = p[i]; }
#pragma unroll
        for (int sh = 1; sh < 16; sh <<= 1)
#pragma unroll
            for (int i = 0; i < 4; ++i) rs[i] += __shfl_xor(rs[i], sh);
        if (lr == 0) *(float4*)&ssum[w][lg * 4] = make_float4(rs[0], rs[1], rs[2], rs[3]);
        {
            ushort4 pb;
            pb.x = f2bf(p[0]); pb.y = f2bf(p[1]); pb.z = f2bf(p[2]); pb.w = f2bf(p[3]);
            *(ushort4*)&plds[(w * 16 + lr) * 16 + lg * 4] = pb;
        }
        __syncthreads();
#pragma unroll
        for (int i = 0; i < 4; ++i) {
            int h = lg * 4 + i;
            float ts = ssum[0][h] + ssum[1][h] + ssum[2][h] + ssum[3][h];
            lsum[i] = lsum[i] * scl[i] + ts;
        }
#pragma unroll
        for (int nt = 0; nt < 8; ++nt)
#pragma unroll
            for (int i = 0; i < 4; ++i) oacc[nt][i] *= scl[i];
#pragma unroll
        for (int kb = 0; kb < 2; ++kb) {
            short8v af;
#pragma unroll
            for (int j = 0; j < 8; ++j)
                af[j] = (short)plds[(kb * 32 + lg * 8 + j) * 16 + lr];
#pragma unroll
            for (int nt = 0; nt < 8; ++nt) {
                int d = w * 128 + nt * 16 + lr;
                short8v bf;
#pragma unroll
                for (int j = 0; j < 8; ++j) {
                    int key = kb * 32 + lg * 8 + j;
                    int addr = (key * 1152 + d * 2) ^ ((key & 7) << 4);
                    bf[j] = *(const short*)((char*)kh + addr);
                }
                oacc[nt] = __builtin_amdgcn_mfma_f32_16x16x32_bf16(af, bf, oacc[nt], 0, 0, 0);
            }
        }
    }
    float inv[4];
#pragma unroll
    for (int i = 0; i < 4; ++i) inv[i] = 1.f / lsum[i];
    unsigned short* ob = ocomp + (size_t)qi * 16 * 512;
#pragma unroll
    for (int nt = 0; nt < 8; ++nt) {
        int d = w * 128 + nt * 16 + lr;
#pragma unroll
        for (int i = 0; i < 4; ++i) {
            int h = lg * 4 + i;
            ob[h * 512 + d] = f2bf(oacc[nt][i] * inv[i]);
        }
    }
}

// ---------------- launcher ----------------
extern "C" void kernel_launch(void* const* d_in, const int* in_sizes, int n_in,
                              void* d_out, int out_size, void* d_ws, size_t ws_size,
                              hipStream_t stream) {
    (void)in_sizes; (void)n_in; (void)out_size; (void)ws_size;
    const float* hidden      = (const float*)d_in[0];
    const float* q_a_w       = (const float*)d_in[1];
    const float* q_a_ln_w    = (const float*)d_in[2];
    const float* q_b_w       = (const float*)d_in[3];
    const float* kv_a_w      = (const float*)d_in[4];
    const float* kv_a_ln_w   = (const float*)d_in[5];
    const float* kv_b_w      = (const float*)d_in[6];
    const float* o_w         = (const float*)d_in[7];
    const float* idx_wq_b_w  = (const float*)d_in[8];
    const float* idx_wk_w    = (const float*)d_in[9];
    const float* idx_kn_w    = (const float*)d_in[10];
    const float* idx_kn_b    = (const float*)d_in[11];
    const float* idx_wproj_w = (const float*)d_in[12];
    float* out = (float*)d_out;

    char* ws = (char*)d_ws;
    size_t off = 0;
    auto alloc = [&](size_t nbytes) -> void* {
        void* p = ws + off;
        off = (off + nbytes + 255) & ~(size_t)255;
        return p;
    };
    // persistent
    float* cos_t = (float*)alloc((size_t)SEQ * 32 * 4);
    float* sin_t = (float*)alloc((size_t)SEQ * 32 * 4);
    float* qbuf  = (float*)alloc((size_t)SEQ * 3072 * 4);
    float* ckv   = (float*)alloc((size_t)SEQ * 576 * 4);
    float* ckvn  = (float*)alloc((size_t)SEQ * KVRANK * 4);
    int*   sel   = (int*)alloc((size_t)SEQ * TOPK * 4);
    unsigned short* khg      = (unsigned short*)alloc((size_t)SEQ * 576 * 2);
    unsigned short* attno_bf = (unsigned short*)alloc((size_t)SEQ * 2048 * 2);
    unsigned short* qr_bf    = (unsigned short*)alloc((size_t)SEQ * QRANK * 2);
    unsigned short* q_b_bf   = (unsigned short*)alloc((size_t)3072 * QRANK * 2);
    unsigned short* kv_a_bf  = (unsigned short*)alloc((size_t)576 * HIDD * 2);
    unsigned short* o_w_bf   = (unsigned short*)alloc((size_t)HIDD * 2048 * 2);
    unsigned short* kv_b_bf  = (unsigned short*)alloc((size_t)4096 * 512 * 2);
    unsigned short* wkt      = (unsigned short*)alloc((size_t)16 * 512 * 128 * 2);
    size_t mark = off;
    // transients (dead after topk)
    float* qr    = (float*)alloc((size_t)SEQ * QRANK * 4);
    float* ccat  = (float*)alloc((size_t)SEQ * NCAT * 4);
    float* scores = (float*)alloc((size_t)SEQ * SEQ * 4);
    unsigned short* iqh = (unsigned short*)alloc((size_t)SEQ * 2048 * 2);
    unsigned short* iql = (unsigned short*)alloc((size_t)SEQ * 2048 * 2);
    unsigned short* ikh = (unsigned short*)alloc((size_t)SEQ * 128 * 2);
    unsigned short* ikl = (unsigned short*)alloc((size_t)SEQ * 128 * 2);
    // overlay region (alive after topk)
    off = mark;
    unsigned short* qabsb = (unsigned short*)alloc((size_t)SEQ * 16 * 512 * 2);
    unsigned short* ocomp = (unsigned short*)alloc((size_t)SEQ * 16 * 512 * 2);

    rope_table_kernel<<<dim3(SEQ), dim3(32), 0, stream>>>(cos_t, sin_t);

    // weight converts (main path)
    cvt_bf16_kernel<<<1024, 256, 0, stream>>>(q_b_w, q_b_bf, 3072 * QRANK / 4);
    cvt_bf16_kernel<<<1024, 256, 0, stream>>>(kv_a_w, kv_a_bf, 576 * HIDD / 4);
    cvt_bf16_kernel<<<1024, 256, 0, stream>>>(o_w, o_w_bf, HIDD * 2048 / 4);
    cvt_bf16_kernel<<<1024, 256, 0, stream>>>(kv_b_w, kv_b_bf, 4096 * 512 / 4);
    wkt_kernel<<<4096, 256, 0, stream>>>(kv_b_w, wkt);

    // fused cat-GEMM: ccat = hidden @ [q_a_w; idx_wk_w; 0.25*idx_wproj_w]^T  (split-MFMA)
    gemm_cat_split_kernel<<<dim3(16, 14), 256, 0, stream>>>(hidden, q_a_w, idx_wk_w, idx_wproj_w, ccat);

    // qr = rmsnorm(ccat[:, :1536]) -> f32 + bf16
    rmsnorm_kernel<<<SEQ, 256, 0, stream>>>(ccat, q_a_ln_w, qr, qr_bf, QRANK, NCAT);

    // ik = rope(layernorm(ccat[:, 1536:1664])) -> hi/lo split
    ln_rope_split_kernel<<<SEQ, 64, 0, stream>>>(ccat + 1536, NCAT, idx_kn_w, idx_kn_b, cos_t, sin_t, ikh, ikl);

    // q = qr @ q_b_w^T (bf16 MFMA); rope [128:192] per head
    mfma_nt_kernel<unsigned short, float><<<dim3(16, 24, 1), 256, 0, stream>>>(
        qr_bf, q_b_bf, qbuf, SEQ, 3072, QRANK, QRANK, QRANK, 3072, 0L, 0L, 0L);
    rope_apply_kernel<<<(SEQ * 16 * 32) / 256, 256, 0, stream>>>(qbuf, cos_t, sin_t, 16, 3072, 192, 128);

    // ckv = hidden @ kv_a_w^T (MFMA); rope kpe; rmsnorm -> ckvn; khg
    mfma_nt_kernel<float, float><<<dim3(16, 5, 1), 256, 0, stream>>>(
        hidden, kv_a_bf, ckv, SEQ, 576, HIDD, HIDD, HIDD, 576, 0L, 0L, 0L);
    rope_apply_kernel<<<(SEQ * 32) / 256, 256, 0, stream>>>(ckv, cos_t, sin_t, 1, 576, 0, 512);
    rmsnorm_kernel<<<SEQ, 256, 0, stream>>>(ckv, kv_a_ln_w, ckvn, nullptr, KVRANK, 576);
    khg_kernel<<<SEQ, 256, 0, stream>>>(ckvn, ckv, khg);

    // iq = rope(qr @ idx_wq_b_w^T) -> hi/lo split (split-MFMA, fused epilogue)
    gemm_iq_split_kernel<<<dim3(16, 16), 256, 0, stream>>>(qr, idx_wq_b_w, cos_t, sin_t, iqh, iql);

    // indexer scores (split-MFMA) + topk
    idx_scores_mfma_kernel<<<dim3(32, 32), 256, 0, stream>>>(iqh, iql, ikh, ikl, ccat + 1664, NCAT, scores);
    topk_kernel<<<SEQ, 1024, 0, stream>>>(scores, sel);

    // q absorption (bf16 MFMA, batched per head)
    mfma_nt_kernel<float, unsigned short><<<dim3(16, 4, 16), 256, 0, stream>>>(
        qbuf, wkt, qabsb, SEQ, 512, 128, 3072, 128, 16 * 512,
        192L, 512L * 128L, 512L);

    // MFMA flash attention over selected keys -> ocomp (normalized bf16)
    attn_mfma_kernel<<<SEQ, 256, 0, stream>>>(qabsb, qbuf, khg, sel, ocomp);

    // output projection (bf16 MFMA, batched)
    mfma_nt_kernel<unsigned short, unsigned short><<<dim3(16, 1, 16), 256, 0, stream>>>(
        ocomp, kv_b_bf + (size_t)128 * 512, attno_bf, SEQ, 128, 512,
        16 * 512, 512, 2048, 512L, 256L * 512L, 128L);

    // out = attno @ o_w^T (bf16 MFMA)
    mfma_nt_kernel<unsigned short, float><<<dim3(16, 16, 1), 256, 0, stream>>>(
        attno_bf, o_w_bf, out, SEQ, HIDD, 2048, 2048, 2048, HIDD, 0L, 0L, 0L);
}

// Round 7
// 926.721 us; speedup vs baseline: 5.1776x; 1.1761x over previous
//
#include <hip/hip_runtime.h>
#include <hip/hip_bf16.h>
#include <math.h>

#define SEQ 2048
#define HIDD 2048
#define QRANK 1536
#define KVRANK 512
#define TOPK 512
#define EPSF 1e-6f
#define SCALE_ATTN 0.07216878364870323f  /* 192^-0.5 */
#define NCAT 1680

typedef __attribute__((ext_vector_type(8))) short short8v;
typedef __attribute__((ext_vector_type(4))) short short4v;
typedef __attribute__((ext_vector_type(4))) float f32x4;

__device__ inline unsigned short f2bf(float f) {
    unsigned u = __float_as_uint(f);
    unsigned r = (u + 0x7FFFu + ((u >> 16) & 1u)) >> 16;
    return (unsigned short)r;
}
__device__ inline float bf2f(unsigned short b) {
    return __uint_as_float(((unsigned)b) << 16);
}
__device__ inline void split2(float x, unsigned short& h, unsigned short& l) {
    h = f2bf(x);
    l = f2bf(x - bf2f(h));
}

// HW transpose read: 4 bf16 at p + j*32B (j=0..3). Builtin handles addrspace + waitcnt.
__device__ inline short4v ds_read_tr16(const void* p) {
#if __has_builtin(__builtin_amdgcn_ds_read_tr16_b64)
    return __builtin_amdgcn_ds_read_tr16_b64((short4v*)p);
#else
    const unsigned short* u = (const unsigned short*)p;
    short4v r;
    r[0] = (short)u[0]; r[1] = (short)u[16]; r[2] = (short)u[32]; r[3] = (short)u[48];
    return r;
#endif
}

// ---------------- RoPE cos/sin table ----------------
__global__ void rope_table_kernel(float* __restrict__ cos_t, float* __restrict__ sin_t) {
    int s = blockIdx.x;
    int i = threadIdx.x;  // 0..31
    double inv = pow(10000.0, -((double)(2 * i)) / 64.0);
    double f = (double)s * inv;
    cos_t[s * 32 + i] = (float)cos(f);
    sin_t[s * 32 + i] = (float)sin(f);
}

// ---------------- f32 -> bf16 convert ----------------
__global__ __launch_bounds__(256) void cvt_bf16_kernel(const float* __restrict__ in,
                                                       unsigned short* __restrict__ out, int n4) {
    for (int i = blockIdx.x * 256 + threadIdx.x; i < n4; i += gridDim.x * 256) {
        float4 v = ((const float4*)in)[i];
        ushort4 o;
        o.x = f2bf(v.x); o.y = f2bf(v.y); o.z = f2bf(v.z); o.w = f2bf(v.w);
        ((ushort4*)out)[i] = o;
    }
}

// ---------------- transpose k-absorb weights: wkt[h][n][d] = kv_b_w[h*256+d][n] ----------------
__global__ __launch_bounds__(256) void wkt_kernel(const float* __restrict__ kvb,
                                                  unsigned short* __restrict__ wkt) {
    int o = blockIdx.x * 256 + threadIdx.x;
    int d = o & 127;
    int n = (o >> 7) & 511;
    int h = o >> 16;
    wkt[o] = f2bf(kvb[((size_t)(h * 256 + d)) * 512 + n]);
}

// ---------------- kh_g[s][0:512]=bf16(ckvn[s]); [512:576]=bf16(roped kpe) ----------------
__global__ __launch_bounds__(256) void khg_kernel(const float* __restrict__ ckvn,
                                                  const float* __restrict__ ckv,
                                                  unsigned short* __restrict__ khg) {
    int s = blockIdx.x;
    for (int i = threadIdx.x; i < 576; i += 256) {
        float v = (i < 512) ? ckvn[(size_t)s * 512 + i] : ckv[(size_t)s * 576 + i];
        khg[(size_t)s * 576 + i] = f2bf(v);
    }
}

// ---------------- split-bf16 3-pass MFMA cat-GEMM ----------------
__global__ __launch_bounds__(256) void gemm_cat_split_kernel(
    const float* __restrict__ hidden, const float* __restrict__ q_a_w,
    const float* __restrict__ idx_wk_w, const float* __restrict__ idx_wproj_w,
    float* __restrict__ ccat)
{
    __shared__ __align__(16) unsigned short Ah[128 * 32], Al[128 * 32];
    __shared__ __align__(16) unsigned short Bh[128 * 32], Bl[128 * 32];
    int tid = threadIdx.x;
    int l = tid & 63, w = tid >> 6;
    int wr = w >> 1, wc = w & 1;
    int m0 = blockIdx.x * 128, n0 = blockIdx.y * 128;
    f32x4 acc[4][4] = {};
    for (int k0 = 0; k0 < HIDD; k0 += 32) {
        __syncthreads();
#pragma unroll
        for (int i = 0; i < 2; ++i) {
            int idx = tid + i * 256;
            int r = idx >> 2, cc = idx & 3;
            int sw = cc ^ (r & 3);
            {
                const float* src = hidden + (size_t)(m0 + r) * HIDD + k0 + cc * 8;
                float4 f0 = *(const float4*)src, f1 = *(const float4*)(src + 4);
                float xs[8] = {f0.x, f0.y, f0.z, f0.w, f1.x, f1.y, f1.z, f1.w};
                short8v dh, dl;
#pragma unroll
                for (int e = 0; e < 8; ++e) {
                    unsigned short hh, ll; split2(xs[e], hh, ll);
                    dh[e] = (short)hh; dl[e] = (short)ll;
                }
                *(short8v*)&Ah[r * 32 + sw * 8] = dh;
                *(short8v*)&Al[r * 32 + sw * 8] = dl;
            }
            {
                int gb = n0 + r; if (gb > NCAT - 1) gb = NCAT - 1;
                float scale = 1.f;
                const float* src;
                if (gb < 1536) src = q_a_w + (size_t)gb * HIDD;
                else if (gb < 1664) src = idx_wk_w + (size_t)(gb - 1536) * HIDD;
                else { src = idx_wproj_w + (size_t)(gb - 1664) * HIDD; scale = 0.25f; }
                src += k0 + cc * 8;
                float4 f0 = *(const float4*)src, f1 = *(const float4*)(src + 4);
                float xs[8] = {f0.x, f0.y, f0.z, f0.w, f1.x, f1.y, f1.z, f1.w};
                short8v dh, dl;
#pragma unroll
                for (int e = 0; e < 8; ++e) {
                    unsigned short hh, ll; split2(xs[e] * scale, hh, ll);
                    dh[e] = (short)hh; dl[e] = (short)ll;
                }
                *(short8v*)&Bh[r * 32 + sw * 8] = dh;
                *(short8v*)&Bl[r * 32 + sw * 8] = dl;
            }
        }
        __syncthreads();
        short8v avh[4], avl[4];
#pragma unroll
        for (int mt = 0; mt < 4; ++mt) {
            int row = wr * 64 + mt * 16 + (l & 15);
            int ch = (l >> 4) ^ (row & 3);
            avh[mt] = *(const short8v*)&Ah[row * 32 + ch * 8];
            avl[mt] = *(const short8v*)&Al[row * 32 + ch * 8];
        }
#pragma unroll
        for (int nt = 0; nt < 4; ++nt) {
            int row = wc * 64 + nt * 16 + (l & 15);
            int ch = (l >> 4) ^ (row & 3);
            short8v bvh = *(const short8v*)&Bh[row * 32 + ch * 8];
            short8v bvl = *(const short8v*)&Bl[row * 32 + ch * 8];
#pragma unroll
            for (int mt = 0; mt < 4; ++mt) {
                acc[mt][nt] = __builtin_amdgcn_mfma_f32_16x16x32_bf16(avh[mt], bvh, acc[mt][nt], 0, 0, 0);
                acc[mt][nt] = __builtin_amdgcn_mfma_f32_16x16x32_bf16(avh[mt], bvl, acc[mt][nt], 0, 0, 0);
                acc[mt][nt] = __builtin_amdgcn_mfma_f32_16x16x32_bf16(avl[mt], bvh, acc[mt][nt], 0, 0, 0);
            }
        }
    }
#pragma unroll
    for (int mt = 0; mt < 4; ++mt)
#pragma unroll
        for (int nt = 0; nt < 4; ++nt)
#pragma unroll
            for (int i = 0; i < 4; ++i) {
                int gm = m0 + wr * 64 + mt * 16 + (l >> 4) * 4 + i;
                int gn = n0 + wc * 64 + nt * 16 + (l & 15);
                if (gn < NCAT) ccat[(size_t)gm * NCAT + gn] = acc[mt][nt][i];
            }
}

// ---------------- split-bf16 3-pass MFMA iq-GEMM with fused RoPE + hi/lo split output ----------------
__global__ __launch_bounds__(256) void gemm_iq_split_kernel(
    const float* __restrict__ qr, const float* __restrict__ wq,
    const float* __restrict__ cos_t, const float* __restrict__ sin_t,
    unsigned short* __restrict__ iqh, unsigned short* __restrict__ iql)
{
    __shared__ __align__(16) unsigned short Ah[128 * 32], Al[128 * 32];
    __shared__ __align__(16) unsigned short Bh[128 * 32], Bl[128 * 32];
    int tid = threadIdx.x;
    int l = tid & 63, w = tid >> 6;
    int wr = w >> 1, wc = w & 1;
    int m0 = blockIdx.x * 128, n0 = blockIdx.y * 128;
    int hh_ = blockIdx.y;  // head
    f32x4 acc[4][4] = {};
    for (int k0 = 0; k0 < QRANK; k0 += 32) {
        __syncthreads();
#pragma unroll
        for (int i = 0; i < 2; ++i) {
            int idx = tid + i * 256;
            int r = idx >> 2, cc = idx & 3;
            int sw = cc ^ (r & 3);
            {
                const float* src = qr + (size_t)(m0 + r) * QRANK + k0 + cc * 8;
                float4 f0 = *(const float4*)src, f1 = *(const float4*)(src + 4);
                float xs[8] = {f0.x, f0.y, f0.z, f0.w, f1.x, f1.y, f1.z, f1.w};
                short8v dh, dl;
#pragma unroll
                for (int e = 0; e < 8; ++e) {
                    unsigned short h2, l2; split2(xs[e], h2, l2);
                    dh[e] = (short)h2; dl[e] = (short)l2;
                }
                *(short8v*)&Ah[r * 32 + sw * 8] = dh;
                *(short8v*)&Al[r * 32 + sw * 8] = dl;
            }
            {
                const float* src = wq + (size_t)(n0 + r) * QRANK + k0 + cc * 8;
                float4 f0 = *(const float4*)src, f1 = *(const float4*)(src + 4);
                float xs[8] = {f0.x, f0.y, f0.z, f0.w, f1.x, f1.y, f1.z, f1.w};
                short8v dh, dl;
#pragma unroll
                for (int e = 0; e < 8; ++e) {
                    unsigned short h2, l2; split2(xs[e], h2, l2);
                    dh[e] = (short)h2; dl[e] = (short)l2;
                }
                *(short8v*)&Bh[r * 32 + sw * 8] = dh;
                *(short8v*)&Bl[r * 32 + sw * 8] = dl;
            }
        }
        __syncthreads();
        short8v avh[4], avl[4];
#pragma unroll
        for (int mt = 0; mt < 4; ++mt) {
            int row = wr * 64 + mt * 16 + (l & 15);
            int ch = (l >> 4) ^ (row & 3);
            avh[mt] = *(const short8v*)&Ah[row * 32 + ch * 8];
            avl[mt] = *(const short8v*)&Al[row * 32 + ch * 8];
        }
#pragma unroll
        for (int nt = 0; nt < 4; ++nt) {
            int row = wc * 64 + nt * 16 + (l & 15);
            int ch = (l >> 4) ^ (row & 3);
            short8v bvh = *(const short8v*)&Bh[row * 32 + ch * 8];
            short8v bvl = *(const short8v*)&Bl[row * 32 + ch * 8];
#pragma unroll
            for (int mt = 0; mt < 4; ++mt) {
                acc[mt][nt] = __builtin_amdgcn_mfma_f32_16x16x32_bf16(avh[mt], bvh, acc[mt][nt], 0, 0, 0);
                acc[mt][nt] = __builtin_amdgcn_mfma_f32_16x16x32_bf16(avh[mt], bvl, acc[mt][nt], 0, 0, 0);
                acc[mt][nt] = __builtin_amdgcn_mfma_f32_16x16x32_bf16(avl[mt], bvh, acc[mt][nt], 0, 0, 0);
            }
        }
    }
    if (wc == 0) {
#pragma unroll
        for (int mt = 0; mt < 4; ++mt)
#pragma unroll
            for (int nt = 0; nt < 2; ++nt)
#pragma unroll
                for (int i = 0; i < 4; ++i) {
                    int q = m0 + wr * 64 + mt * 16 + (l >> 4) * 4 + i;
                    int dd = nt * 16 + (l & 15);
                    float c = cos_t[q * 32 + dd], s = sin_t[q * 32 + dd];
                    float x1 = acc[mt][nt][i], x2 = acc[mt][nt + 2][i];
                    acc[mt][nt][i] = x1 * c - x2 * s;
                    acc[mt][nt + 2][i] = x2 * c + x1 * s;
                }
    }
#pragma unroll
    for (int mt = 0; mt < 4; ++mt)
#pragma unroll
        for (int nt = 0; nt < 4; ++nt)
#pragma unroll
            for (int i = 0; i < 4; ++i) {
                int q = m0 + wr * 64 + mt * 16 + (l >> 4) * 4 + i;
                int d = wc * 64 + nt * 16 + (l & 15);
                size_t idx = ((size_t)q * 16 + hh_) * 128 + d;
                unsigned short h2, l2; split2(acc[mt][nt][i], h2, l2);
                iqh[idx] = h2; iql[idx] = l2;
            }
}

// ---------------- bf16 MFMA NT GEMM, batched (main path) ----------------
template <typename TA, typename TC>
__global__ __launch_bounds__(256) void mfma_nt_kernel(
    const TA* __restrict__ A, const unsigned short* __restrict__ B, TC* __restrict__ C,
    int M, int N, int K, int lda, int ldb, int ldc, long ab, long bb, long cb)
{
    __shared__ __align__(16) unsigned short Asl[128 * 32];
    __shared__ __align__(16) unsigned short Bsl[128 * 32];
    int z = blockIdx.z;
    const TA* Az = A + (size_t)z * ab;
    const unsigned short* Bz = B + (size_t)z * bb;
    TC* Cz = C + (size_t)z * cb;
    int tid = threadIdx.x;
    int l = tid & 63, w = tid >> 6;
    int wr = w >> 1, wc = w & 1;
    int m0 = blockIdx.x * 128, n0 = blockIdx.y * 128;
    f32x4 acc[4][4] = {};

    for (int k0 = 0; k0 < K; k0 += 32) {
        __syncthreads();
#pragma unroll
        for (int i = 0; i < 2; ++i) {
            int idx = tid + i * 256;
            int r = idx >> 2, cc = idx & 3;
            int sw = cc ^ (r & 3);
            {
                short8v d;
                const TA* src = Az + (size_t)(m0 + r) * lda + k0 + cc * 8;
                if constexpr (sizeof(TA) == 2) {
                    d = *(const short8v*)src;
                } else {
                    float4 f0 = *(const float4*)src;
                    float4 f1 = *(const float4*)(src + 4);
                    d[0] = (short)f2bf(f0.x); d[1] = (short)f2bf(f0.y);
                    d[2] = (short)f2bf(f0.z); d[3] = (short)f2bf(f0.w);
                    d[4] = (short)f2bf(f1.x); d[5] = (short)f2bf(f1.y);
                    d[6] = (short)f2bf(f1.z); d[7] = (short)f2bf(f1.w);
                }
                *(short8v*)&Asl[r * 32 + sw * 8] = d;
            }
            {
                int gb = n0 + r; if (gb > N - 1) gb = N - 1;
                short8v d = *(const short8v*)(Bz + (size_t)gb * ldb + k0 + cc * 8);
                *(short8v*)&Bsl[r * 32 + sw * 8] = d;
            }
        }
        __syncthreads();
        short8v av[4], bv[4];
#pragma unroll
        for (int mt = 0; mt < 4; ++mt) {
            int row = wr * 64 + mt * 16 + (l & 15);
            int ch = (l >> 4) ^ (row & 3);
            av[mt] = *(const short8v*)&Asl[row * 32 + ch * 8];
        }
#pragma unroll
        for (int nt = 0; nt < 4; ++nt) {
            int row = wc * 64 + nt * 16 + (l & 15);
            int ch = (l >> 4) ^ (row & 3);
            bv[nt] = *(const short8v*)&Bsl[row * 32 + ch * 8];
        }
#pragma unroll
        for (int mt = 0; mt < 4; ++mt)
#pragma unroll
            for (int nt = 0; nt < 4; ++nt)
                acc[mt][nt] = __builtin_amdgcn_mfma_f32_16x16x32_bf16(av[mt], bv[nt], acc[mt][nt], 0, 0, 0);
    }
#pragma unroll
    for (int mt = 0; mt < 4; ++mt) {
#pragma unroll
        for (int nt = 0; nt < 4; ++nt) {
#pragma unroll
            for (int i = 0; i < 4; ++i) {
                int gm = m0 + wr * 64 + mt * 16 + (l >> 4) * 4 + i;
                int gn = n0 + wc * 64 + nt * 16 + (l & 15);
                if (gn < N) {
                    float v = acc[mt][nt][i];
                    if constexpr (sizeof(TC) == 4) Cz[(size_t)gm * ldc + gn] = v;
                    else Cz[(size_t)gm * ldc + gn] = f2bf(v);
                }
            }
        }
    }
}

// ---------------- RMSNorm, optional bf16 secondary output ----------------
__global__ __launch_bounds__(256) void rmsnorm_kernel(
    const float* __restrict__ in, const float* __restrict__ w, float* __restrict__ out,
    unsigned short* __restrict__ bf_out, int n, int in_stride)
{
    int row = blockIdx.x, tid = threadIdx.x;
    const float* x = in + (size_t)row * in_stride;
    float4 v[2];
    int cnt = 0;
    float ss = 0.f;
    int nf4 = n >> 2;
    for (int i = tid; i < nf4; i += 256) {
        float4 t = *(const float4*)(x + i * 4);
        v[cnt++] = t;
        ss += t.x * t.x + t.y * t.y + t.z * t.z + t.w * t.w;
    }
#pragma unroll
    for (int m = 32; m; m >>= 1) ss += __shfl_xor(ss, m);
    __shared__ float red[8];
    int wid = tid >> 6;
    if ((tid & 63) == 0) red[wid] = ss;
    __syncthreads();
    if (tid == 0) {
        float s = red[0] + red[1] + red[2] + red[3];
        red[4] = rsqrtf(s / (float)n + EPSF);
    }
    __syncthreads();
    float scale = red[4];
    cnt = 0;
    for (int i = tid; i < nf4; i += 256) {
        float4 t = v[cnt++];
        float4 wv = *(const float4*)(w + i * 4);
        float4 o;
        o.x = t.x * scale * wv.x; o.y = t.y * scale * wv.y;
        o.z = t.z * scale * wv.z; o.w = t.w * scale * wv.w;
        *(float4*)(out + (size_t)row * n + i * 4) = o;
        if (bf_out) {
            ushort4 ob;
            ob.x = f2bf(o.x); ob.y = f2bf(o.y); ob.z = f2bf(o.z); ob.w = f2bf(o.w);
            *(ushort4*)(bf_out + (size_t)row * n + i * 4) = ob;
        }
    }
}

// ---------------- LayerNorm + RoPE + hi/lo split for ik ----------------
__global__ __launch_bounds__(64) void ln_rope_split_kernel(
    const float* __restrict__ in, int stride,
    const float* __restrict__ w, const float* __restrict__ b,
    const float* __restrict__ cos_t, const float* __restrict__ sin_t,
    unsigned short* __restrict__ ikh, unsigned short* __restrict__ ikl)
{
    int row = blockIdx.x, tid = threadIdx.x;
    const float* x = in + (size_t)row * stride;
    float x0 = x[tid], x1 = x[tid + 64];
    float s = x0 + x1, ss = x0 * x0 + x1 * x1;
#pragma unroll
    for (int m = 32; m; m >>= 1) { s += __shfl_xor(s, m); ss += __shfl_xor(ss, m); }
    float mean = s * (1.f / 128.f);
    float var = ss * (1.f / 128.f) - mean * mean;
    float r = rsqrtf(var + EPSF);
    float n0 = (x0 - mean) * r * w[tid] + b[tid];
    float n1 = (x1 - mean) * r * w[tid + 64] + b[tid + 64];
    float c = cos_t[row * 32 + (tid & 31)], sn = sin_t[row * 32 + (tid & 31)];
    float other = __shfl_xor(n0, 32);
    float r0 = (tid < 32) ? (n0 * c - other * sn) : (n0 * c + other * sn);
    unsigned short h2, l2;
    split2(r0, h2, l2);
    ikh[(size_t)row * 128 + tid] = h2; ikl[(size_t)row * 128 + tid] = l2;
    split2(n1, h2, l2);
    ikh[(size_t)row * 128 + 64 + tid] = h2; ikl[(size_t)row * 128 + 64 + tid] = l2;
}

// ---------------- RoPE in-place ----------------
__global__ void rope_apply_kernel(
    float* __restrict__ x, const float* __restrict__ cos_t, const float* __restrict__ sin_t,
    int heads, int row_stride, int head_stride, int offset)
{
    int t = blockIdx.x * blockDim.x + threadIdx.x;
    int i = t & 31;
    int hh = (t >> 5) % heads;
    int r = t / (32 * heads);
    if (r >= SEQ) return;
    float* p = x + (size_t)r * row_stride + hh * head_stride + offset;
    float c = cos_t[r * 32 + i], s = sin_t[r * 32 + i];
    float x1 = p[i], x2 = p[i + 32];
    p[i] = x1 * c - x2 * s;
    p[i + 32] = x2 * c + x1 * s;
}

// ---------------- indexer scores via split-bf16 3-pass MFMA ----------------
__global__ __launch_bounds__(256) void idx_scores_mfma_kernel(
    const unsigned short* __restrict__ iqh, const unsigned short* __restrict__ iql,
    const unsigned short* __restrict__ ikh, const unsigned short* __restrict__ ikl,
    const float* __restrict__ iwsrc, int iw_stride,
    float* __restrict__ scores)
{
    int q0 = blockIdx.x * 64, k0 = blockIdx.y * 64;
    int tid = threadIdx.x;
    if (k0 > q0 + 63) {
        for (int t = tid; t < 64 * 64; t += 256) {
            int r = t >> 6, c = t & 63;
            scores[(size_t)(q0 + r) * SEQ + k0 + c] = -INFINITY;
        }
        return;
    }
    __shared__ __align__(16) unsigned short skh[64 * 128], skl[64 * 128];
    __shared__ __align__(16) unsigned short sqh[64 * 128], sql[64 * 128];
    __shared__ float iws[64][16];
    int l = tid & 63, w = tid >> 6;
    for (int it = tid; it < 64 * 16; it += 256) {
        int r = it >> 4, c = it & 15;
        int sw = c ^ (r & 15);
        *(short8v*)&skh[r * 128 + sw * 8] = *(const short8v*)(ikh + (size_t)(k0 + r) * 128 + c * 8);
        *(short8v*)&skl[r * 128 + sw * 8] = *(const short8v*)(ikl + (size_t)(k0 + r) * 128 + c * 8);
    }
    {
        int r = tid >> 2, c = tid & 3;
        *(float4*)&iws[r][c * 4] = *(const float4*)(iwsrc + (size_t)(q0 + r) * iw_stride + c * 4);
    }
    f32x4 acc[4] = {};
    for (int h = 0; h < 16; ++h) {
        __syncthreads();
        for (int it = tid; it < 64 * 16; it += 256) {
            int r = it >> 4, c = it & 15;
            int sw = c ^ (r & 15);
            size_t base = ((size_t)(q0 + r) * 16 + h) * 128 + c * 8;
            *(short8v*)&sqh[r * 128 + sw * 8] = *(const short8v*)(iqh + base);
            *(short8v*)&sql[r * 128 + sw * 8] = *(const short8v*)(iql + base);
        }
        __syncthreads();
        f32x4 dot[4] = {};
#pragma unroll
        for (int ks = 0; ks < 4; ++ks) {
            int arow = w * 16 + (l & 15);
            int ach = ((l >> 4) + ks * 4) ^ (arow & 15);
            short8v ah = *(const short8v*)&sqh[arow * 128 + ach * 8];
            short8v al = *(const short8v*)&sql[arow * 128 + ach * 8];
#pragma unroll
            for (int nt = 0; nt < 4; ++nt) {
                int brow = nt * 16 + (l & 15);
                int bch = ((l >> 4) + ks * 4) ^ (brow & 15);
                short8v bh = *(const short8v*)&skh[brow * 128 + bch * 8];
                short8v bl = *(const short8v*)&skl[brow * 128 + bch * 8];
                dot[nt] = __builtin_amdgcn_mfma_f32_16x16x32_bf16(ah, bh, dot[nt], 0, 0, 0);
                dot[nt] = __builtin_amdgcn_mfma_f32_16x16x32_bf16(ah, bl, dot[nt], 0, 0, 0);
                dot[nt] = __builtin_amdgcn_mfma_f32_16x16x32_bf16(al, bh, dot[nt], 0, 0, 0);
            }
        }
#pragma unroll
        for (int nt = 0; nt < 4; ++nt)
#pragma unroll
            for (int i = 0; i < 4; ++i) {
                float wv = iws[w * 16 + (l >> 4) * 4 + i][h];
                acc[nt][i] += wv * fmaxf(dot[nt][i], 0.f);
            }
    }
#pragma unroll
    for (int nt = 0; nt < 4; ++nt)
#pragma unroll
        for (int i = 0; i < 4; ++i) {
            int q = q0 + w * 16 + (l >> 4) * 4 + i;
            int k = k0 + nt * 16 + (l & 15);
            scores[(size_t)q * SEQ + k] = (k <= q) ? acc[nt][i] : -INFINITY;
        }
}

// ---------------- top-512 per row via bitonic sort ----------------
__global__ __launch_bounds__(1024) void topk_kernel(
    const float* __restrict__ scores, int* __restrict__ sel)
{
    int qi = blockIdx.x, tid = threadIdx.x;
    __shared__ unsigned long long keys[2048];
    const float* srow = scores + (size_t)qi * SEQ;
#pragma unroll
    for (int r = 0; r < 2; ++r) {
        int k = tid + r * 1024;
        unsigned u = __float_as_uint(srow[k]);
        unsigned mv = (u & 0x80000000u) ? ~u : (u | 0x80000000u);
        keys[k] = ((unsigned long long)mv << 32) | (unsigned)(2047 - k);
    }
    for (int ksz = 2; ksz <= 2048; ksz <<= 1) {
        for (int j = ksz >> 1; j > 0; j >>= 1) {
            __syncthreads();
#pragma unroll 1
            for (int r = 0; r < 2; ++r) {
                int i = tid + r * 1024;
                int ixj = i ^ j;
                if (ixj > i) {
                    unsigned long long a = keys[i], b = keys[ixj];
                    bool dir = ((i & ksz) == 0);
                    if ((a < b) == dir) { keys[i] = b; keys[ixj] = a; }
                }
            }
        }
    }
    __syncthreads();
    if (tid < TOPK) {
        int k = 2047 - (int)(keys[tid] & 0xFFFFFFFFu);
        sel[(size_t)qi * TOPK + tid] = (tid <= qi) ? k : -1;
    }
}

// ---------------- MFMA flash-style absorbed sparse attention (tr_b16 PV) ----------------
// LDS layout:
//   [0, 66560)       : V subtiled [32 dblocks][64 keys][16 d] bf16, dblock stride 2080B (+32B pad)
//   [66560, 74752)   : kpe row-major [64][64] bf16, XOR-swizzled byte^((key&7)<<4)
//   [74752, 76800)   : plds [64 keys][16 heads] bf16
//   [76800, ...)     : smax[4][16], ssum[4][16], selb[64]
__global__ __launch_bounds__(256) void attn_mfma_kernel(
    const unsigned short* __restrict__ qabs,  // (S,16,512) bf16
    const float* __restrict__ qsrc,           // qbuf (S,16,192) f32, qpe at +128
    const unsigned short* __restrict__ khg,   // (S,576) bf16: [ckvn|kpe]
    const int* __restrict__ sel,              // (S,512)
    unsigned short* __restrict__ ocomp)       // (S,16,512) bf16 normalized
{
    __shared__ __align__(16) char smem[77568];
    unsigned short* plds = (unsigned short*)(smem + 74752);
    float* smax = (float*)(smem + 76800);   // [4][16]
    float* ssum = (float*)(smem + 77056);   // [4][16]
    int* selb   = (int*)(smem + 77312);     // [64]

    const int qi = blockIdx.x;
    const int tid = threadIdx.x;
    const int l = tid & 63, w = tid >> 6;
    const int lg = l >> 4, lr = l & 15;
    const int nv = min(TOPK, qi + 1);
    const int ntile = (nv + 63) >> 6;
    const int krow = w * 16 + lr;

    // A-fragments: qh[head=lr][k = lg*8 + ks*32 .. +8]
    short8v aq[18];
    {
        const unsigned short* qa = qabs + ((size_t)qi * 16 + lr) * 512 + lg * 8;
#pragma unroll
        for (int ks = 0; ks < 16; ++ks)
            aq[ks] = *(const short8v*)(qa + ks * 32);
        const float* qp = qsrc + (size_t)qi * 3072 + lr * 192 + 128 + lg * 8;
#pragma unroll
        for (int ks = 0; ks < 2; ++ks) {
            float4 f0 = *(const float4*)(qp + ks * 32);
            float4 f1 = *(const float4*)(qp + ks * 32 + 4);
            short8v d;
            d[0] = (short)f2bf(f0.x); d[1] = (short)f2bf(f0.y);
            d[2] = (short)f2bf(f0.z); d[3] = (short)f2bf(f0.w);
            d[4] = (short)f2bf(f1.x); d[5] = (short)f2bf(f1.y);
            d[6] = (short)f2bf(f1.z); d[7] = (short)f2bf(f1.w);
            aq[16 + ks] = d;
        }
    }

    // byte base for score-phase V reads: key=krow, dblock=(lg>>1), 16B half=(lg&1)
    const int sbase = krow * 32 + (lg >> 1) * 2080 + (lg & 1) * 16;
    // byte base for tr_b16 PV reads: dblock = w*8 (+nt), key0 = lg*8 (+kb*32), col = lr
    const int vboff = w * 16640 + lg * 256 + lr * 2;

    float m[4] = {-1e30f, -1e30f, -1e30f, -1e30f};
    float lsum[4] = {0.f, 0.f, 0.f, 0.f};
    f32x4 oacc[8] = {};

    for (int t = 0; t < ntile; ++t) {
        const int j0 = t * 64;
        __syncthreads();
        if (tid < 64) {
            int sv = sel[(size_t)qi * TOPK + j0 + tid];
            selb[tid] = sv < 0 ? 0 : sv;
        }
        __syncthreads();
        // stage V part into subtiled layout (vectorized 16B writes)
        for (int it = tid; it < 64 * 64; it += 256) {
            int key = it >> 6, c = it & 63;
            short8v v = *(const short8v*)(khg + (size_t)selb[key] * 576 + c * 8);
            *(short8v*)(smem + (c >> 1) * 2080 + key * 32 + (c & 1) * 16) = v;
        }
        // stage kpe part (row-major, XOR swizzle)
        for (int it = tid; it < 64 * 8; it += 256) {
            int key = it >> 3, c = it & 7;
            short8v v = *(const short8v*)(khg + (size_t)selb[key] * 576 + 512 + c * 8);
            *(short8v*)(smem + 66560 + ((key * 128 + c * 16) ^ ((key & 7) << 4))) = v;
        }
        __syncthreads();
        // scores for wave's 16 keys
        f32x4 s = {};
#pragma unroll
        for (int ks = 0; ks < 16; ++ks) {
            short8v b = *(const short8v*)(smem + sbase + ks * 4160);
            s = __builtin_amdgcn_mfma_f32_16x16x32_bf16(aq[ks], b, s, 0, 0, 0);
        }
#pragma unroll
        for (int ks = 0; ks < 2; ++ks) {
            short8v b = *(const short8v*)(smem + 66560 +
                ((krow * 128 + ks * 64 + lg * 16) ^ ((krow & 7) << 4)));
            s = __builtin_amdgcn_mfma_f32_16x16x32_bf16(aq[16 + ks], b, s, 0, 0, 0);
        }
        bool kvalid = (j0 + krow) < nv;
#pragma unroll
        for (int i = 0; i < 4; ++i)
            s[i] = kvalid ? s[i] * SCALE_ATTN : -1e30f;
        float tm[4];
#pragma unroll
        for (int i = 0; i < 4; ++i) tm[i] = s[i];
#pragma unroll
        for (int sh = 1; sh < 16; sh <<= 1)
#pragma unroll
            for (int i = 0; i < 4; ++i) tm[i] = fmaxf(tm[i], __shfl_xor(tm[i], sh));
        if (lr == 0) *(float4*)&smax[w * 16 + lg * 4] = make_float4(tm[0], tm[1], tm[2], tm[3]);
        __syncthreads();
        float mn[4], scl[4];
#pragma unroll
        for (int i = 0; i < 4; ++i) {
            int h = lg * 4 + i;
            float tmax = fmaxf(fmaxf(smax[h], smax[16 + h]), fmaxf(smax[32 + h], smax[48 + h]));
            mn[i] = fmaxf(m[i], tmax);
            scl[i] = __expf(m[i] - mn[i]);
            m[i] = mn[i];
        }
        float p[4], rs[4];
#pragma unroll
        for (int i = 0; i < 4; ++i) { p[i] = __expf(s[i] - mn[i]); rs[i] = p[i]; }
#pragma unroll
        for (int sh = 1; sh < 16; sh <<= 1)
#pragma unroll
            for (int i = 0; i < 4; ++i) rs[i] += __shfl_xor(rs[i], sh);
        if (lr == 0) *(float4*)&ssum[w * 16 + lg * 4] = make_float4(rs[0], rs[1], rs[2], rs[3]);
        {
            ushort4 pb;
            pb.x = f2bf(p[0]); pb.y = f2bf(p[1]); pb.z = f2bf(p[2]); pb.w = f2bf(p[3]);
            *(ushort4*)&plds[(w * 16 + lr) * 16 + lg * 4] = pb;
        }
        __syncthreads();
#pragma unroll
        for (int i = 0; i < 4; ++i) {
            int h = lg * 4 + i;
            float ts = ssum[h] + ssum[16 + h] + ssum[32 + h] + ssum[48 + h];
            lsum[i] = lsum[i] * scl[i] + ts;
        }
#pragma unroll
        for (int nt = 0; nt < 8; ++nt)
#pragma unroll
            for (int i = 0; i < 4; ++i) oacc[nt][i] *= scl[i];
        // PV: wave handles dims [w*128, w*128+128); B-frags via ds_read_tr16 (HW transpose)
#pragma unroll
        for (int kb = 0; kb < 2; ++kb) {
            short8v af;
#pragma unroll
            for (int j = 0; j < 8; ++j)
                af[j] = (short)plds[(kb * 32 + lg * 8 + j) * 16 + lr];
#pragma unroll
            for (int nt = 0; nt < 8; ++nt) {
                const char* a = smem + vboff + kb * 1024 + nt * 2080;
                short4v t0 = ds_read_tr16(a);          // keys +0..3  (elem j at +32B)
                short4v t1 = ds_read_tr16(a + 128);    // keys +4..7
                short8v bf = __builtin_shufflevector(t0, t1, 0, 1, 2, 3, 4, 5, 6, 7);
                oacc[nt] = __builtin_amdgcn_mfma_f32_16x16x32_bf16(af, bf, oacc[nt], 0, 0, 0);
            }
        }
    }
    float inv[4];
#pragma unroll
    for (int i = 0; i < 4; ++i) inv[i] = 1.f / lsum[i];
    unsigned short* ob = ocomp + (size_t)qi * 16 * 512;
#pragma unroll
    for (int nt = 0; nt < 8; ++nt) {
        int d = w * 128 + nt * 16 + lr;
#pragma unroll
        for (int i = 0; i < 4; ++i) {
            int h = lg * 4 + i;
            ob[h * 512 + d] = f2bf(oacc[nt][i] * inv[i]);
        }
    }
}

// ---------------- launcher ----------------
extern "C" void kernel_launch(void* const* d_in, const int* in_sizes, int n_in,
                              void* d_out, int out_size, void* d_ws, size_t ws_size,
                              hipStream_t stream) {
    (void)in_sizes; (void)n_in; (void)out_size; (void)ws_size;
    const float* hidden      = (const float*)d_in[0];
    const float* q_a_w       = (const float*)d_in[1];
    const float* q_a_ln_w    = (const float*)d_in[2];
    const float* q_b_w       = (const float*)d_in[3];
    const float* kv_a_w      = (const float*)d_in[4];
    const float* kv_a_ln_w   = (const float*)d_in[5];
    const float* kv_b_w      = (const float*)d_in[6];
    const float* o_w         = (const float*)d_in[7];
    const float* idx_wq_b_w  = (const float*)d_in[8];
    const float* idx_wk_w    = (const float*)d_in[9];
    const float* idx_kn_w    = (const float*)d_in[10];
    const float* idx_kn_b    = (const float*)d_in[11];
    const float* idx_wproj_w = (const float*)d_in[12];
    float* out = (float*)d_out;

    char* ws = (char*)d_ws;
    size_t off = 0;
    auto alloc = [&](size_t nbytes) -> void* {
        void* p = ws + off;
        off = (off + nbytes + 255) & ~(size_t)255;
        return p;
    };
    // persistent
    float* cos_t = (float*)alloc((size_t)SEQ * 32 * 4);
    float* sin_t = (float*)alloc((size_t)SEQ * 32 * 4);
    float* qbuf  = (float*)alloc((size_t)SEQ * 3072 * 4);
    float* ckv   = (float*)alloc((size_t)SEQ * 576 * 4);
    float* ckvn  = (float*)alloc((size_t)SEQ * KVRANK * 4);
    int*   sel   = (int*)alloc((size_t)SEQ * TOPK * 4);
    unsigned short* khg      = (unsigned short*)alloc((size_t)SEQ * 576 * 2);
    unsigned short* attno_bf = (unsigned short*)alloc((size_t)SEQ * 2048 * 2);
    unsigned short* qr_bf    = (unsigned short*)alloc((size_t)SEQ * QRANK * 2);
    unsigned short* q_b_bf   = (unsigned short*)alloc((size_t)3072 * QRANK * 2);
    unsigned short* kv_a_bf  = (unsigned short*)alloc((size_t)576 * HIDD * 2);
    unsigned short* o_w_bf   = (unsigned short*)alloc((size_t)HIDD * 2048 * 2);
    unsigned short* kv_b_bf  = (unsigned short*)alloc((size_t)4096 * 512 * 2);
    unsigned short* wkt      = (unsigned short*)alloc((size_t)16 * 512 * 128 * 2);
    size_t mark = off;
    // transients (dead after topk)
    float* qr    = (float*)alloc((size_t)SEQ * QRANK * 4);
    float* ccat  = (float*)alloc((size_t)SEQ * NCAT * 4);
    float* scores = (float*)alloc((size_t)SEQ * SEQ * 4);
    unsigned short* iqh = (unsigned short*)alloc((size_t)SEQ * 2048 * 2);
    unsigned short* iql = (unsigned short*)alloc((size_t)SEQ * 2048 * 2);
    unsigned short* ikh = (unsigned short*)alloc((size_t)SEQ * 128 * 2);
    unsigned short* ikl = (unsigned short*)alloc((size_t)SEQ * 128 * 2);
    // overlay region (alive after topk)
    off = mark;
    unsigned short* qabsb = (unsigned short*)alloc((size_t)SEQ * 16 * 512 * 2);
    unsigned short* ocomp = (unsigned short*)alloc((size_t)SEQ * 16 * 512 * 2);

    rope_table_kernel<<<dim3(SEQ), dim3(32), 0, stream>>>(cos_t, sin_t);

    // weight converts (main path)
    cvt_bf16_kernel<<<1024, 256, 0, stream>>>(q_b_w, q_b_bf, 3072 * QRANK / 4);
    cvt_bf16_kernel<<<1024, 256, 0, stream>>>(kv_a_w, kv_a_bf, 576 * HIDD / 4);
    cvt_bf16_kernel<<<1024, 256, 0, stream>>>(o_w, o_w_bf, HIDD * 2048 / 4);
    cvt_bf16_kernel<<<1024, 256, 0, stream>>>(kv_b_w, kv_b_bf, 4096 * 512 / 4);
    wkt_kernel<<<4096, 256, 0, stream>>>(kv_b_w, wkt);

    // fused cat-GEMM: ccat = hidden @ [q_a_w; idx_wk_w; 0.25*idx_wproj_w]^T  (split-MFMA)
    gemm_cat_split_kernel<<<dim3(16, 14), 256, 0, stream>>>(hidden, q_a_w, idx_wk_w, idx_wproj_w, ccat);

    // qr = rmsnorm(ccat[:, :1536]) -> f32 + bf16
    rmsnorm_kernel<<<SEQ, 256, 0, stream>>>(ccat, q_a_ln_w, qr, qr_bf, QRANK, NCAT);

    // ik = rope(layernorm(ccat[:, 1536:1664])) -> hi/lo split
    ln_rope_split_kernel<<<SEQ, 64, 0, stream>>>(ccat + 1536, NCAT, idx_kn_w, idx_kn_b, cos_t, sin_t, ikh, ikl);

    // q = qr @ q_b_w^T (bf16 MFMA); rope [128:192] per head
    mfma_nt_kernel<unsigned short, float><<<dim3(16, 24, 1), 256, 0, stream>>>(
        qr_bf, q_b_bf, qbuf, SEQ, 3072, QRANK, QRANK, QRANK, 3072, 0L, 0L, 0L);
    rope_apply_kernel<<<(SEQ * 16 * 32) / 256, 256, 0, stream>>>(qbuf, cos_t, sin_t, 16, 3072, 192, 128);

    // ckv = hidden @ kv_a_w^T (MFMA); rope kpe; rmsnorm -> ckvn; khg
    mfma_nt_kernel<float, float><<<dim3(16, 5, 1), 256, 0, stream>>>(
        hidden, kv_a_bf, ckv, SEQ, 576, HIDD, HIDD, HIDD, 576, 0L, 0L, 0L);
    rope_apply_kernel<<<(SEQ * 32) / 256, 256, 0, stream>>>(ckv, cos_t, sin_t, 1, 576, 0, 512);
    rmsnorm_kernel<<<SEQ, 256, 0, stream>>>(ckv, kv_a_ln_w, ckvn, nullptr, KVRANK, 576);
    khg_kernel<<<SEQ, 256, 0, stream>>>(ckvn, ckv, khg);

    // iq = rope(qr @ idx_wq_b_w^T) -> hi/lo split (split-MFMA, fused epilogue)
    gemm_iq_split_kernel<<<dim3(16, 16), 256, 0, stream>>>(qr, idx_wq_b_w, cos_t, sin_t, iqh, iql);

    // indexer scores (split-MFMA) + topk
    idx_scores_mfma_kernel<<<dim3(32, 32), 256, 0, stream>>>(iqh, iql, ikh, ikl, ccat + 1664, NCAT, scores);
    topk_kernel<<<SEQ, 1024, 0, stream>>>(scores, sel);

    // q absorption (bf16 MFMA, batched per head)
    mfma_nt_kernel<float, unsigned short><<<dim3(16, 4, 16), 256, 0, stream>>>(
        qbuf, wkt, qabsb, SEQ, 512, 128, 3072, 128, 16 * 512,
        192L, 512L * 128L, 512L);

    // MFMA flash attention over selected keys -> ocomp (normalized bf16)
    attn_mfma_kernel<<<SEQ, 256, 0, stream>>>(qabsb, qbuf, khg, sel, ocomp);

    // output projection (bf16 MFMA, batched)
    mfma_nt_kernel<unsigned short, unsigned short><<<dim3(16, 1, 16), 256, 0, stream>>>(
        ocomp, kv_b_bf + (size_t)128 * 512, attno_bf, SEQ, 128, 512,
        16 * 512, 512, 2048, 512L, 256L * 512L, 128L);

    // out = attno @ o_w^T (bf16 MFMA)
    mfma_nt_kernel<unsigned short, float><<<dim3(16, 16, 1), 256, 0, stream>>>(
        attno_bf, o_w_bf, out, SEQ, HIDD, 2048, 2048, 2048, HIDD, 0L, 0L, 0L);
}